// Round 2
// baseline (10480.645 us; speedup 1.0000x reference)
//
#include <hip/hip_runtime.h>
#include <cstdint>

// DA_RNN particle filter, B=128 T=32 H=256 K=32 — persistent-kernel version.
// One block per batch b (128 blocks x 1024 threads, cooperative launch).
// h-state in LDS, c-state in L2-resident global. The ONLY cross-b coupling is
// the resampling softmax denominator (torch-reshape quirk: mixes 32 batches of
// a b-group at fixed rank) -> one 32-block group barrier per step via
// device-scope atomics on per-step slots.
// ALL floating-point chains are operand-for-operand identical to the round-1
// bit-exact (absmax 0.0) version — only thread assignment changed.

#define Bn 128
#define Tn 32
#define Hn 256
#define Kn 32
#define TPB 1024

__host__ __device__ inline void tf2x32(uint32_t k0, uint32_t k1, uint32_t x0, uint32_t x1,
                                       uint32_t &o0, uint32_t &o1) {
  uint32_t ks2 = k0 ^ k1 ^ 0x1BD11BDAu;
  x0 += k0; x1 += k1;
#define TFR(r) { x0 += x1; x1 = (x1 << r) | (x1 >> (32 - r)); x1 ^= x0; }
  TFR(13) TFR(15) TFR(26) TFR(6)
  x0 += k1;  x1 += ks2 + 1u;
  TFR(17) TFR(29) TFR(16) TFR(24)
  x0 += ks2; x1 += k0 + 2u;
  TFR(13) TFR(15) TFR(26) TFR(6)
  x0 += k0;  x1 += k1 + 3u;
  TFR(17) TFR(29) TFR(16) TFR(24)
  x0 += k1;  x1 += ks2 + 4u;
  TFR(13) TFR(15) TFR(26) TFR(6)
  x0 += ks2; x1 += k0 + 5u;
#undef TFR
  o0 = x0; o1 = x1;
}

__device__ __forceinline__ float erfinv_xla(float x) {
  float w = -log1pf(-x * x);
  float p;
  if (w < 5.0f) {
    w = w - 2.5f;
    p = 2.81022636e-08f;
    p = fmaf(p, w, 3.43273939e-07f);
    p = fmaf(p, w, -3.5233877e-06f);
    p = fmaf(p, w, -4.39150654e-06f);
    p = fmaf(p, w, 0.00021858087f);
    p = fmaf(p, w, -0.00125372503f);
    p = fmaf(p, w, -0.00417768164f);
    p = fmaf(p, w, 0.246640727f);
    p = fmaf(p, w, 1.50140941f);
  } else {
    w = sqrtf(w) - 3.0f;
    p = -0.000200214257f;
    p = fmaf(p, w, 0.000100950558f);
    p = fmaf(p, w, 0.00134934322f);
    p = fmaf(p, w, -0.00367342844f);
    p = fmaf(p, w, 0.00573950773f);
    p = fmaf(p, w, -0.0076224613f);
    p = fmaf(p, w, 0.00943887047f);
    p = fmaf(p, w, 1.00167406f);
    p = fmaf(p, w, 2.83297682f);
  }
  return p * x;
}

__device__ __forceinline__ float sigmoid_xla(float x) {
  return 0.5f + 0.5f * tanhf(0.5f * x);
}

__device__ __forceinline__ float u01_from_bits(uint32_t bits) {
  return __uint_as_float((bits >> 9) | 0x3F800000u) - 1.0f;
}

__device__ __forceinline__ float normal_from_idx(uint32_t ka, uint32_t kb, uint32_t idx) {
  uint32_t o0, o1; tf2x32(ka, kb, 0u, idx, o0, o1);
  float f = u01_from_bits(o0 ^ o1);
  const float LO = __uint_as_float(0xBF7FFFFFu);
  float u = fmaxf(LO, f * 2.0f + LO);
  return __uint_as_float(0x3FB504F3u) * erfinv_xla(u);
}

__device__ __forceinline__ float gumbel_from_idx(uint32_t ka, uint32_t kb, uint32_t idx) {
  uint32_t o0, o1; tf2x32(ka, kb, 0u, idx, o0, o1);
  float f = u01_from_bits(o0 ^ o1);
  const float TINY = __uint_as_float(0x00800000u);
  float u = fmaxf(TINY, f + TINY);
  return -logf(-logf(u));
}

// ---------------- precompute kernels (launched once, plain) ----------------

// bid<768: W1hT/W1cT/W1eT transposes; 768..1023: WhhT gate-interleaved;
// 1024..1280: varWT transpose.
__global__ void darnn_p0(const float* __restrict__ W1, const float* __restrict__ Whh,
                         const float* __restrict__ varW,
                         float* __restrict__ W1hT, float* __restrict__ W1cT,
                         float* __restrict__ W1eT, float* __restrict__ WhhT,
                         float* __restrict__ varWT) {
  int bid = blockIdx.x, tid = threadIdx.x;
  if (bid < 768) {
    int part = bid >> 8, j = bid & 255;
    float v = W1[tid * 768 + part * 256 + j];
    float* dst = (part == 0) ? W1hT : (part == 1) ? W1cT : W1eT;
    dst[j * 256 + tid] = v;
  } else if (bid < 1024) {
    int j = bid - 768;
    for (int idx = tid; idx < 1024; idx += 256) {
      int h = idx >> 2, q = idx & 3;
      WhhT[j * 1024 + idx] = Whh[(q * 256 + h) * 256 + j];
    }
  } else {
    int j2 = bid - 1024;  // 0..256
    varWT[j2 * 256 + tid] = varW[tid * 257 + j2];
  }
}

__global__ void darnn_p1(const float* __restrict__ enc, const float* __restrict__ W1eT,
                         const float* __restrict__ b1, float* __restrict__ encW1) {
  int bt = blockIdx.x, tid = threadIdx.x;
  __shared__ float se[256];
  se[tid] = enc[bt * 256 + tid];
  __syncthreads();
  float acc = 0.f;
  for (int j = 0; j < 256; ++j) acc = fmaf(se[j], W1eT[j * 256 + tid], acc);
  encW1[bt * 256 + tid] = acc + b1[tid];
}

// ---------------- persistent per-batch kernel ----------------

__launch_bounds__(TPB)
__global__ void darnn_main(const float* __restrict__ enc, const float* __restrict__ yprev,
                           const float* __restrict__ W1hT, const float* __restrict__ W1cT,
                           const float* __restrict__ encW1, const float* __restrict__ W2,
                           const float* __restrict__ b2p, const float* __restrict__ fcW,
                           const float* __restrict__ fcbp, const float* __restrict__ varWT,
                           const float* __restrict__ varb, const float* __restrict__ WhhT,
                           const float* __restrict__ Wih, const float* __restrict__ bih,
                           const float* __restrict__ bhh, const float* __restrict__ decW,
                           const float* __restrict__ decbp, const float* __restrict__ pdfW,
                           const float* __restrict__ pdfbp, const float* __restrict__ encWo,
                           const float* __restrict__ encbo,
                           float* __restrict__ cbuf, float* __restrict__ wex,
                           int* __restrict__ bar, float* __restrict__ out) {
  const int b = blockIdx.x, tid = threadIdx.x;
  const int bg = b >> 5;
  const int h = tid & 255, kg = tid >> 8;   // kg in [0,4): 8 k-rows each
  const int lane = tid & 63;

  __shared__ __align__(16) float sh_h[32 * 256];          // 32 KB: particle h-state
  __shared__ float s_hm[256], s_cm[256], s_hmc[256], s_ctx[256], s_std[256], s_red[256];
  __shared__ float s_sc[32], s_beta[32];
  __shared__ float s_ytl;
  __shared__ float s_sredP[32 * 4], s_sredQ[32 * 4];      // proj/pdot wave partials
  __shared__ float s_proj[32], s_pdot[32], s_w[32], s_logit[32];
  __shared__ int s_srck[32], s_samp[32];

  float* cb = cbuf + (size_t)b * 32 * 256;

  // zero state
  for (int i = tid; i < 32 * 256; i += TPB) { sh_h[i] = 0.f; cb[i] = 0.f; }
  __threadfence_block();
  __syncthreads();

  // hoisted per-thread weight scalars (per-h columns)
  const float bI = bih[h], bF = bih[256 + h], bG = bih[512 + h], bO = bih[768 + h];
  const float dI = bhh[h], dF = bhh[256 + h], dG = bhh[512 + h], dO = bhh[768 + h];
  const float wI = Wih[h], wF = Wih[256 + h], wG = Wih[512 + h], wO = Wih[768 + h];
  const float dw = decW[h], pw = pdfW[h];

  for (int t = 0; t < Tn; ++t) {
    uint32_t f0, f1, k1a, k1b, k2a, k2b;
    tf2x32(0u, 42u, 0u, (uint32_t)t, f0, f1);
    tf2x32(f0, f1, 0u, 0u, k1a, k1b);
    tf2x32(f0, f1, 0u, 1u, k2a, k2b);

    // ---- phase A: particle means (serial over k, exact round-1 order) ----
    if (tid < 256) {
      float s = 0.f;
      for (int k = 0; k < 32; ++k) s += sh_h[k * 256 + tid];
      s_hm[tid] = s * 0.03125f;
    } else if (tid < 512) {
      int j = tid & 255;
      float s = 0.f;
      for (int k = 0; k < 32; ++k) s += cb[k * 256 + j];
      s_cm[j] = s * 0.03125f;
    }
    __syncthreads();
    // hmc GEMV: serial interleaved h/c chain (exact round-1 order)
    if (tid < 256) {
      float acc = 0.f;
      for (int j = 0; j < 256; ++j) {
        acc = fmaf(s_hm[j], W1hT[j * 256 + tid], acc);
        acc = fmaf(s_cm[j], W1cT[j * 256 + tid], acc);
      }
      s_hmc[tid] = acc;
    }
    __syncthreads();

    // ---- phase B: attention scores (lane-strided-64 partial + shfl tree) ----
    {
      int wv = tid >> 6;
      for (int tt = wv * 2; tt < wv * 2 + 2; ++tt) {
        float p = 0.f;
        for (int hh = lane; hh < 256; hh += 64)
          p += tanhf(encW1[(b * 32 + tt) * 256 + hh] + s_hmc[hh]) * W2[hh];
        for (int off = 32; off; off >>= 1) p += __shfl_down(p, off);
        if (lane == 0) s_sc[tt] = p + b2p[0];
      }
    }
    __syncthreads();
    if (tid == 0) {
      float m = s_sc[0];
      for (int k = 1; k < 32; ++k) m = fmaxf(m, s_sc[k]);
      float s = 0.f;
      for (int k = 0; k < 32; ++k) { float e = expf(s_sc[k] - m); s_beta[k] = e; s += e; }
      for (int k = 0; k < 32; ++k) s_beta[k] /= s;
    }
    __syncthreads();

    // ---- phase C: context + y_tilde ----
    if (tid < 256) {
      float cx = 0.f;
      for (int tt = 0; tt < 32; ++tt) cx = fmaf(s_beta[tt], enc[(b * 32 + tt) * 256 + tid], cx);
      s_ctx[tid] = cx;
      s_red[tid] = cx * fcW[tid];
    }
    __syncthreads();
    if (tid == 0) {
      float s = 0.f;
      for (int j = 0; j < 256; ++j) s += s_red[j];
      s += yprev[b * 32 + t] * fcW[256];
      s_ytl = s + fcbp[0];
    }
    __syncthreads();

    // ---- phase D: var head -> std ----
    if (tid < 256) {
      float v = s_ytl * varWT[tid];
      for (int j = 0; j < 256; ++j) v = fmaf(s_hm[j], varWT[(1 + j) * 256 + tid], v);
      v += varb[tid];
      s_std[tid] = fmaxf(v, 0.f) + log1pf(expf(-fabsf(v)));
    }
    __syncthreads();

    // ---- phase E: LSTM GEMM + activations + reparam noise ----
    float ai[8], af[8], ag[8], ao[8];
#pragma unroll
    for (int r = 0; r < 8; ++r) { ai[r] = af[r] = ag[r] = ao[r] = 0.f; }
    {
      const float4* wp = (const float4*)WhhT + h;
      const float* shr = sh_h + kg * 8 * 256;
      for (int j = 0; j < 256; j += 4) {
        float4 w0 = wp[(j + 0) * 256];
        float4 w1 = wp[(j + 1) * 256];
        float4 w2 = wp[(j + 2) * 256];
        float4 w3 = wp[(j + 3) * 256];
#pragma unroll
        for (int r = 0; r < 8; ++r) {
          float4 h4 = *(const float4*)(shr + r * 256 + j);
          ai[r] = fmaf(h4.x, w0.x, ai[r]); ai[r] = fmaf(h4.y, w1.x, ai[r]);
          ai[r] = fmaf(h4.z, w2.x, ai[r]); ai[r] = fmaf(h4.w, w3.x, ai[r]);
          af[r] = fmaf(h4.x, w0.y, af[r]); af[r] = fmaf(h4.y, w1.y, af[r]);
          af[r] = fmaf(h4.z, w2.y, af[r]); af[r] = fmaf(h4.w, w3.y, af[r]);
          ag[r] = fmaf(h4.x, w0.z, ag[r]); ag[r] = fmaf(h4.y, w1.z, ag[r]);
          ag[r] = fmaf(h4.z, w2.z, ag[r]); ag[r] = fmaf(h4.w, w3.z, ag[r]);
          ao[r] = fmaf(h4.x, w0.w, ao[r]); ao[r] = fmaf(h4.y, w1.w, ao[r]);
          ao[r] = fmaf(h4.z, w2.w, ao[r]); ao[r] = fmaf(h4.w, w3.w, ao[r]);
        }
      }
    }
    float hnv[8], cnv[8];
    {
      float xb = s_ytl;
#pragma unroll
      for (int r = 0; r < 8; ++r) {
        int k = kg * 8 + r;
        int row = k * 128 + b;
        float pi = ((xb * wI + bI) + ai[r]) + dI;
        float pf = ((xb * wF + bF) + af[r]) + dF;
        float pg = ((xb * wG + bG) + ag[r]) + dG;
        float po = ((xb * wO + bO) + ao[r]) + dO;
        float c_old = cb[k * 256 + h];
        float cn = sigmoid_xla(pf) * c_old + sigmoid_xla(pi) * tanhf(pg);
        float hn = sigmoid_xla(po) * tanhf(cn);
        float eps = normal_from_idx(k1a, k1b, (uint32_t)(row * 256 + h));
        hn = hn + eps * s_std[h];
        cnv[r] = cn;
        hnv[r] = hn;
      }
    }

    // ---- phase F: proj/pdot per-row reductions (exact round-1 tree) ----
#pragma unroll
    for (int r = 0; r < 8; ++r) {
      int k = kg * 8 + r;
      float v = hnv[r] * dw;
      for (int off = 32; off; off >>= 1) v += __shfl_down(v, off);
      if (lane == 0) s_sredP[k * 4 + (h >> 6)] = v;
      float v2 = hnv[r] * pw;
      for (int off = 32; off; off >>= 1) v2 += __shfl_down(v2, off);
      if (lane == 0) s_sredQ[k * 4 + (h >> 6)] = v2;
    }
    __syncthreads();
    if (tid < 32) {
      int k = tid;
      s_proj[k] = ((s_sredP[k * 4 + 0] + s_sredP[k * 4 + 1]) +
                   (s_sredP[k * 4 + 2] + s_sredP[k * 4 + 3])) + decbp[0];
    } else if (tid < 64) {
      int k = tid - 32;
      s_pdot[k] = (s_sredQ[k * 4 + 0] + s_sredQ[k * 4 + 1]) +
                  (s_sredQ[k * 4 + 2] + s_sredQ[k * 4 + 3]);
    }
    __syncthreads();

    // ---- phase G: stable argsort ranks + particle weights + group exchange ----
    float* wex_t = wex + t * (32 * 128);
    if (tid < 32) {
      float p = s_proj[tid];
      int rank = 0;
      for (int kk = 0; kk < 32; ++kk) {
        float q = s_proj[kk];
        rank += (q < p) || (q == p && kk < tid);
      }
      s_srck[rank] = tid;
      float wv_ = expf((s_pdot[tid] + s_ytl * pdfW[256]) + pdfbp[0]);
      s_w[rank] = wv_;
      wex_t[rank * 128 + b] = wv_;
    }
    __syncthreads();                 // stores complete (waitcnt before barrier)
    if (tid == 0) {
      __threadfence();               // release: writeback to coherent point
      atomicAdd(&bar[bg * 32 + t], 1);
      while (__hip_atomic_load(&bar[bg * 32 + t], __ATOMIC_ACQUIRE,
                               __HIP_MEMORY_SCOPE_AGENT) < 32) {
        __builtin_amdgcn_s_sleep(1);
      }
      __threadfence();               // acquire: invalidate stale lines
    }
    __syncthreads();
    if (tid < 32) {
      // denom over the group's 32 batches at fixed rank (exact round-1 order)
      const float* wr = wex_t + tid * 128 + bg * 32;
      float s = 0.f;
      for (int j2 = 0; j2 < 32; ++j2) s += wr[j2];
      s_logit[tid] = logf(s_w[tid] / s);
    }
    __syncthreads();

    // ---- phase H: Gumbel-argmax categorical ----
    if (tid < 32) {
      int r2 = tid * 128 + b;
      float best = gumbel_from_idx(k2a, k2b, (uint32_t)(r2 * 32)) + s_logit[0];
      int sv = 0;
      for (int k = 1; k < 32; ++k) {
        float v = gumbel_from_idx(k2a, k2b, (uint32_t)(r2 * 32 + k)) + s_logit[k];
        if (v > best) { best = v; sv = k; }
      }
      s_samp[tid] = sv;
    }
    __syncthreads();

    // ---- phase I: resample scatter (h from sorted source, c unsorted) ----
    for (int ko = 0; ko < 32; ++ko) {
      int sc_ = s_samp[ko];
      int shh = s_srck[sc_];
      if ((shh >> 3) == kg) sh_h[ko * 256 + h] = hnv[shh & 7];
      if ((sc_ >> 3) == kg) cb[ko * 256 + h] = cnv[sc_ & 7];
    }
    __threadfence_block();
    __syncthreads();
  }

  // ---- epilogue: final means + output head (exact round-1 trees) ----
  if (tid < 256) {
    float s = 0.f;
    for (int k = 0; k < 32; ++k) s += sh_h[k * 256 + tid];
    s_hm[tid] = s * 0.03125f;
  }
  __syncthreads();
  if (tid < 256) {
    int wvi = tid >> 6;
    float v1 = s_hm[tid] * decW[tid];
    float v2 = s_ctx[tid] * encWo[tid];
    for (int off = 32; off; off >>= 1) { v1 += __shfl_down(v1, off); v2 += __shfl_down(v2, off); }
    if (lane == 0) { s_sredP[wvi] = v1; s_sredP[4 + wvi] = v2; }
  }
  __syncthreads();
  if (tid == 0) {
    float d1 = (s_sredP[0] + s_sredP[1]) + (s_sredP[2] + s_sredP[3]);
    float d2 = (s_sredP[4] + s_sredP[5]) + (s_sredP[6] + s_sredP[7]);
    out[b] = ((d1 + decbp[0]) + d2) + encbo[0];
  }
}

extern "C" void kernel_launch(void* const* d_in, const int* in_sizes, int n_in,
                              void* d_out, int out_size, void* d_ws, size_t ws_size,
                              hipStream_t stream) {
  const float* enc   = (const float*)d_in[0];
  const float* yprev = (const float*)d_in[1];
  const float* W1    = (const float*)d_in[2];
  const float* b1    = (const float*)d_in[3];
  const float* W2    = (const float*)d_in[4];
  const float* b2    = (const float*)d_in[5];
  const float* fcW   = (const float*)d_in[6];
  const float* fcb   = (const float*)d_in[7];
  const float* varW  = (const float*)d_in[8];
  const float* varb  = (const float*)d_in[9];
  const float* Wih   = (const float*)d_in[10];
  const float* Whh   = (const float*)d_in[11];
  const float* bih   = (const float*)d_in[12];
  const float* bhh   = (const float*)d_in[13];
  const float* decW  = (const float*)d_in[14];
  const float* decb  = (const float*)d_in[15];
  const float* pdfW  = (const float*)d_in[16];
  const float* pdfb  = (const float*)d_in[17];
  const float* encWo = (const float*)d_in[18];
  const float* encbo = (const float*)d_in[19];

  float* ws = (float*)d_ws;
  size_t o = 0;
  float* encW1 = ws + o; o += (size_t)Bn * Tn * Hn;    // 1,048,576
  float* W1hT  = ws + o; o += (size_t)Hn * Hn;
  float* W1cT  = ws + o; o += (size_t)Hn * Hn;
  float* W1eT  = ws + o; o += (size_t)Hn * Hn;
  float* WhhT  = ws + o; o += (size_t)Hn * 4 * Hn;     // 262,144
  float* varWT = ws + o; o += (size_t)257 * Hn;        // 65,792
  float* cbuf  = ws + o; o += (size_t)Kn * Bn * Hn;    // 1,048,576
  float* wex   = ws + o; o += (size_t)Tn * Kn * Bn;    // 131,072
  int*   bar   = (int*)(ws + o); o += 128;
  if (ws_size < o * sizeof(float)) return;

  hipMemsetAsync(bar, 0, 128 * sizeof(int), stream);

  darnn_p0<<<1281, 256, 0, stream>>>(W1, Whh, varW, W1hT, W1cT, W1eT, WhhT, varWT);
  darnn_p1<<<Bn * Tn, 256, 0, stream>>>(enc, W1eT, b1, encW1);

  float* outp = (float*)d_out;
  void* args[] = {
    (void*)&enc, (void*)&yprev, (void*)&W1hT, (void*)&W1cT, (void*)&encW1,
    (void*)&W2, (void*)&b2, (void*)&fcW, (void*)&fcb, (void*)&varWT,
    (void*)&varb, (void*)&WhhT, (void*)&Wih, (void*)&bih, (void*)&bhh,
    (void*)&decW, (void*)&decb, (void*)&pdfW, (void*)&pdfb, (void*)&encWo,
    (void*)&encbo, (void*)&cbuf, (void*)&wex, (void*)&bar, (void*)&outp
  };
  hipLaunchCooperativeKernel((void*)darnn_main, dim3(Bn), dim3(TPB), args, 0, stream);
}

// Round 3
// 3651.729 us; speedup vs baseline: 2.8700x; 2.8700x over previous
//
#include <hip/hip_runtime.h>
#include <cstdint>

// DA_RNN particle filter, B=128 T=32 H=256 K=32.
// Round 3: multi-kernel, 2 dispatches/step:
//   ka  (128 blk x 256 thr): resample-sampling for step t-1 (redundant per-b group
//        sort/denom/gumbel -> index maps, NO gather copy), particle means via
//        indirection, attention, y_tilde, var/std.
//   k5  (256 blk x 512 thr): 16-row LSTM GEMM (float4 LDS broadcast reads),
//        cell update, reparam noise, proj/pdot row reductions.
// No device-scope fences (round-2 lesson: agent fences nuke per-XCD L2).
// All fp chains operand-for-operand identical to the round-1 bit-exact version.

#define Bn 128
#define Tn 32
#define Hn 256
#define Kn 32

__host__ __device__ inline void tf2x32(uint32_t k0, uint32_t k1, uint32_t x0, uint32_t x1,
                                       uint32_t &o0, uint32_t &o1) {
  uint32_t ks2 = k0 ^ k1 ^ 0x1BD11BDAu;
  x0 += k0; x1 += k1;
#define TFR(r) { x0 += x1; x1 = (x1 << r) | (x1 >> (32 - r)); x1 ^= x0; }
  TFR(13) TFR(15) TFR(26) TFR(6)
  x0 += k1;  x1 += ks2 + 1u;
  TFR(17) TFR(29) TFR(16) TFR(24)
  x0 += ks2; x1 += k0 + 2u;
  TFR(13) TFR(15) TFR(26) TFR(6)
  x0 += k0;  x1 += k1 + 3u;
  TFR(17) TFR(29) TFR(16) TFR(24)
  x0 += k1;  x1 += ks2 + 4u;
  TFR(13) TFR(15) TFR(26) TFR(6)
  x0 += ks2; x1 += k0 + 5u;
#undef TFR
  o0 = x0; o1 = x1;
}

__device__ __forceinline__ float erfinv_xla(float x) {
  float w = -log1pf(-x * x);
  float p;
  if (w < 5.0f) {
    w = w - 2.5f;
    p = 2.81022636e-08f;
    p = fmaf(p, w, 3.43273939e-07f);
    p = fmaf(p, w, -3.5233877e-06f);
    p = fmaf(p, w, -4.39150654e-06f);
    p = fmaf(p, w, 0.00021858087f);
    p = fmaf(p, w, -0.00125372503f);
    p = fmaf(p, w, -0.00417768164f);
    p = fmaf(p, w, 0.246640727f);
    p = fmaf(p, w, 1.50140941f);
  } else {
    w = sqrtf(w) - 3.0f;
    p = -0.000200214257f;
    p = fmaf(p, w, 0.000100950558f);
    p = fmaf(p, w, 0.00134934322f);
    p = fmaf(p, w, -0.00367342844f);
    p = fmaf(p, w, 0.00573950773f);
    p = fmaf(p, w, -0.0076224613f);
    p = fmaf(p, w, 0.00943887047f);
    p = fmaf(p, w, 1.00167406f);
    p = fmaf(p, w, 2.83297682f);
  }
  return p * x;
}

__device__ __forceinline__ float sigmoid_xla(float x) {
  return 0.5f + 0.5f * tanhf(0.5f * x);
}

__device__ __forceinline__ float u01_from_bits(uint32_t bits) {
  return __uint_as_float((bits >> 9) | 0x3F800000u) - 1.0f;
}

__device__ __forceinline__ float normal_from_idx(uint32_t ka, uint32_t kb, uint32_t idx) {
  uint32_t o0, o1; tf2x32(ka, kb, 0u, idx, o0, o1);
  float f = u01_from_bits(o0 ^ o1);
  const float LO = __uint_as_float(0xBF7FFFFFu);
  float u = fmaxf(LO, f * 2.0f + LO);
  return __uint_as_float(0x3FB504F3u) * erfinv_xla(u);
}

__device__ __forceinline__ float gumbel_from_idx(uint32_t ka, uint32_t kb, uint32_t idx) {
  uint32_t o0, o1; tf2x32(ka, kb, 0u, idx, o0, o1);
  float f = u01_from_bits(o0 ^ o1);
  const float TINY = __uint_as_float(0x00800000u);
  float u = fmaxf(TINY, f + TINY);
  return -logf(-logf(u));
}

// ---------------- precompute ----------------

__global__ void darnn_p0(const float* __restrict__ W1, const float* __restrict__ Whh,
                         const float* __restrict__ varW,
                         float* __restrict__ W1hT, float* __restrict__ W1cT,
                         float* __restrict__ W1eT, float* __restrict__ WhhT,
                         float* __restrict__ varWT) {
  int bid = blockIdx.x, tid = threadIdx.x;
  if (bid < 768) {
    int part = bid >> 8, j = bid & 255;
    float v = W1[tid * 768 + part * 256 + j];
    float* dst = (part == 0) ? W1hT : (part == 1) ? W1cT : W1eT;
    dst[j * 256 + tid] = v;
  } else if (bid < 1024) {
    int j = bid - 768;
    for (int idx = tid; idx < 1024; idx += 256) {
      int h = idx >> 2, q = idx & 3;
      WhhT[j * 1024 + idx] = Whh[(q * 256 + h) * 256 + j];
    }
  } else {
    int j2 = bid - 1024;  // 0..256
    varWT[j2 * 256 + tid] = varW[tid * 257 + j2];
  }
}

__global__ void darnn_p1(const float* __restrict__ enc, const float* __restrict__ W1eT,
                         const float* __restrict__ b1, float* __restrict__ encW1) {
  int bt = blockIdx.x, tid = threadIdx.x;
  __shared__ float se[256];
  se[tid] = enc[bt * 256 + tid];
  __syncthreads();
  float acc = 0.f;
  for (int j = 0; j < 256; ++j) acc = fmaf(se[j], W1eT[j * 256 + tid], acc);
  encW1[bt * 256 + tid] = acc + b1[tid];
}

// ---------------- per-step head kernel: sample(t-1) + means + attention + var ----

__launch_bounds__(256)
__global__ void darnn_ka(const float* __restrict__ enc, const float* __restrict__ yprev,
                         const float* __restrict__ W1hT, const float* __restrict__ W1cT,
                         const float* __restrict__ encW1, const float* __restrict__ W2,
                         const float* __restrict__ b2p, const float* __restrict__ fcW,
                         const float* __restrict__ fcbp, const float* __restrict__ varWT,
                         const float* __restrict__ varb, const float* __restrict__ pdfW,
                         const float* __restrict__ pdfbp,
                         const float* __restrict__ proj_g, const float* __restrict__ pdot_g,
                         const float* __restrict__ ytl_prev,
                         const float* __restrict__ hprev, const float* __restrict__ cprev,
                         int* __restrict__ idxH_g, int* __restrict__ idxC_g,
                         float* __restrict__ ytl_cur, float* __restrict__ std_g,
                         float* __restrict__ ctx_g,
                         int t, uint32_t k2a, uint32_t k2b) {
  const int b = blockIdx.x, tid = threadIdx.x, bg = b >> 5, bloc = b & 31;
  __shared__ float s_gp[1024], s_w[1024];
  __shared__ int s_srck[1024];
  __shared__ float s_ytlp[32], s_den[32], s_logit[32];
  __shared__ int s_row[32], s_rowc[32];
  __shared__ float s_hm[256], s_cm[256], s_hmc[256], s_red[256];
  __shared__ float s_sc[32], s_beta[32];
  __shared__ float s_ytl;

  if (t > 0) {
    if (tid < 32) s_ytlp[tid] = ytl_prev[bg * 32 + tid];
    for (int i = tid; i < 1024; i += 256) {
      int bl = i >> 5, k = i & 31;
      s_gp[i] = proj_g[k * 128 + bg * 32 + bl];
    }
    __syncthreads();
    for (int i = tid; i < 1024; i += 256) {
      int bl = i >> 5, k = i & 31;
      float p = s_gp[i];
      const float* gp = s_gp + bl * 32;
      int rank = 0;
      for (int kk = 0; kk < 32; ++kk) {
        float q = gp[kk];
        rank += (q < p) || (q == p && kk < k);
      }
      s_srck[bl * 32 + rank] = k;
      // round-1 f1 order: exp((pdot + ytl*pdfW[256]) + pdfb)
      float wv = expf((pdot_g[k * 128 + bg * 32 + bl] + s_ytlp[bl] * pdfW[256]) + pdfbp[0]);
      s_w[bl * 32 + rank] = wv;
    }
    __syncthreads();
    if (tid < 32) {
      // denom: sum over group batches ASCENDING at fixed rank (round-1 f2 order)
      float s = 0.f;
      for (int bl = 0; bl < 32; ++bl) s += s_w[bl * 32 + tid];
      s_den[tid] = s;
    }
    __syncthreads();
    if (tid < 32) s_logit[tid] = logf(s_w[bloc * 32 + tid] / s_den[tid]);
    __syncthreads();
    if (tid < 32) {
      int ko = tid, r2 = ko * 128 + b;
      float best = gumbel_from_idx(k2a, k2b, (uint32_t)(r2 * 32)) + s_logit[0];
      int sv = 0;
      for (int k = 1; k < 32; ++k) {
        float v = gumbel_from_idx(k2a, k2b, (uint32_t)(r2 * 32 + k)) + s_logit[k];
        if (v > best) { best = v; sv = k; }
      }
      int sH = s_srck[bloc * 32 + sv];
      s_row[ko] = sH * 128 + b;     // h source row (sorted gather)
      s_rowc[ko] = sv * 128 + b;    // c source row (unsorted gather)
      idxH_g[ko * 128 + b] = sH * 128 + b;
      idxC_g[ko * 128 + b] = sv * 128 + b;
    }
  } else {
    if (tid < 32) {
      s_row[tid] = tid * 128 + b;
      s_rowc[tid] = tid * 128 + b;
      idxH_g[tid * 128 + b] = tid * 128 + b;
      idxC_g[tid * 128 + b] = tid * 128 + b;
    }
  }
  __syncthreads();

  // particle means, k ascending (round-1 k12 order), via indirection
  {
    float s1 = 0.f, s2 = 0.f;
    for (int k = 0; k < 32; ++k) s1 += hprev[(size_t)s_row[k] * 256 + tid];
    for (int k = 0; k < 32; ++k) s2 += cprev[(size_t)s_rowc[k] * 256 + tid];
    s_hm[tid] = s1 * 0.03125f;
    s_cm[tid] = s2 * 0.03125f;
  }
  __syncthreads();
  // hmc GEMV: serial interleaved h/c chain (round-1 order)
  {
    float acc = 0.f;
    for (int j = 0; j < 256; ++j) {
      acc = fmaf(s_hm[j], W1hT[j * 256 + tid], acc);
      acc = fmaf(s_cm[j], W1cT[j * 256 + tid], acc);
    }
    s_hmc[tid] = acc;
  }
  __syncthreads();
  // attention scores (round-1 k3)
  {
    int lane = tid & 63, wv = tid >> 6;
    for (int tt = wv * 8; tt < wv * 8 + 8; ++tt) {
      float p = 0.f;
      for (int hh = lane; hh < 256; hh += 64)
        p += tanhf(encW1[(b * 32 + tt) * 256 + hh] + s_hmc[hh]) * W2[hh];
      for (int off = 32; off; off >>= 1) p += __shfl_down(p, off);
      if (lane == 0) s_sc[tt] = p + b2p[0];
    }
  }
  __syncthreads();
  if (tid == 0) {
    float m = s_sc[0];
    for (int k = 1; k < 32; ++k) m = fmaxf(m, s_sc[k]);
    float s = 0.f;
    for (int k = 0; k < 32; ++k) { float e = expf(s_sc[k] - m); s_beta[k] = e; s += e; }
    for (int k = 0; k < 32; ++k) s_beta[k] /= s;
  }
  __syncthreads();
  // context + y_tilde (round-1 k3)
  {
    float cx = 0.f;
    for (int tt = 0; tt < 32; ++tt) cx = fmaf(s_beta[tt], enc[(b * 32 + tt) * 256 + tid], cx);
    ctx_g[b * 256 + tid] = cx;
    s_red[tid] = cx * fcW[tid];
  }
  __syncthreads();
  if (tid == 0) {
    float s = 0.f;
    for (int j = 0; j < 256; ++j) s += s_red[j];
    s += yprev[b * 32 + t] * fcW[256];
    s_ytl = s + fcbp[0];
    ytl_cur[b] = s_ytl;
  }
  __syncthreads();
  // var head -> std (round-1 k4 via transposed weights, round-2-verified)
  {
    float v = s_ytl * varWT[tid];
    for (int j = 0; j < 256; ++j) v = fmaf(s_hm[j], varWT[(1 + j) * 256 + tid], v);
    v += varb[tid];
    std_g[b * 256 + tid] = fmaxf(v, 0.f) + log1pf(expf(-fabsf(v)));
  }
}

// ---------------- per-step LSTM kernel: 16 rows/block ----------------

__launch_bounds__(512)
__global__ void darnn_k5(const float* __restrict__ hprev, const float* __restrict__ cprev,
                         const int* __restrict__ idxH_g, const int* __restrict__ idxC_g,
                         const float* __restrict__ WhhT, const float* __restrict__ Wih,
                         const float* __restrict__ bih, const float* __restrict__ bhh,
                         const float* __restrict__ ytl_cur, const float* __restrict__ std_g,
                         const float* __restrict__ decW, const float* __restrict__ decbp,
                         const float* __restrict__ pdfW,
                         uint32_t k1a, uint32_t k1b,
                         float* __restrict__ hcur, float* __restrict__ ccur,
                         float* __restrict__ proj_g, float* __restrict__ pdot_g) {
  const int R0 = blockIdx.x * 16, tid = threadIdx.x;
  const int h = tid & 255, kg = tid >> 8, lane = tid & 63;
  __shared__ __align__(16) float s_h[16 * 256];
  __shared__ int s_src[16], s_srcC[16];
  __shared__ float s_sredP[16 * 4], s_sredQ[16 * 4];

  if (tid < 16) { s_src[tid] = idxH_g[R0 + tid]; s_srcC[tid] = idxC_g[R0 + tid]; }
  __syncthreads();
  {
    const float4* hp = (const float4*)hprev;
    float4* sh4 = (float4*)s_h;
    for (int i = tid; i < 1024; i += 512) {
      int rr = i >> 6, c4 = i & 63;
      sh4[i] = hp[(size_t)s_src[rr] * 64 + c4];
    }
  }
  __syncthreads();

  float ai[8], af[8], ag[8], ao[8];
#pragma unroll
  for (int r = 0; r < 8; ++r) { ai[r] = af[r] = ag[r] = ao[r] = 0.f; }
  {
    const float4* wp = (const float4*)WhhT + h;
    const float* shr = s_h + kg * 8 * 256;
    for (int j = 0; j < 256; j += 4) {
      float4 w0 = wp[(j + 0) * 256];
      float4 w1 = wp[(j + 1) * 256];
      float4 w2 = wp[(j + 2) * 256];
      float4 w3 = wp[(j + 3) * 256];
#pragma unroll
      for (int r = 0; r < 8; ++r) {
        float4 h4 = *(const float4*)(shr + r * 256 + j);
        ai[r] = fmaf(h4.x, w0.x, ai[r]); ai[r] = fmaf(h4.y, w1.x, ai[r]);
        ai[r] = fmaf(h4.z, w2.x, ai[r]); ai[r] = fmaf(h4.w, w3.x, ai[r]);
        af[r] = fmaf(h4.x, w0.y, af[r]); af[r] = fmaf(h4.y, w1.y, af[r]);
        af[r] = fmaf(h4.z, w2.y, af[r]); af[r] = fmaf(h4.w, w3.y, af[r]);
        ag[r] = fmaf(h4.x, w0.z, ag[r]); ag[r] = fmaf(h4.y, w1.z, ag[r]);
        ag[r] = fmaf(h4.z, w2.z, ag[r]); ag[r] = fmaf(h4.w, w3.z, ag[r]);
        ao[r] = fmaf(h4.x, w0.w, ao[r]); ao[r] = fmaf(h4.y, w1.w, ao[r]);
        ao[r] = fmaf(h4.z, w2.w, ao[r]); ao[r] = fmaf(h4.w, w3.w, ao[r]);
      }
    }
  }

  const float bI = bih[h], bF = bih[256 + h], bG = bih[512 + h], bO = bih[768 + h];
  const float dI = bhh[h], dF = bhh[256 + h], dG = bhh[512 + h], dO = bhh[768 + h];
  const float wI = Wih[h], wF = Wih[256 + h], wG = Wih[512 + h], wO = Wih[768 + h];
  float hnv[8];
#pragma unroll
  for (int r = 0; r < 8; ++r) {
    int rr = kg * 8 + r, R = R0 + rr, bb = R & 127;
    float xb = ytl_cur[bb];
    float pi = ((xb * wI + bI) + ai[r]) + dI;
    float pf = ((xb * wF + bF) + af[r]) + dF;
    float pg = ((xb * wG + bG) + ag[r]) + dG;
    float po = ((xb * wO + bO) + ao[r]) + dO;
    float c_old = cprev[(size_t)s_srcC[rr] * 256 + h];
    float cn = sigmoid_xla(pf) * c_old + sigmoid_xla(pi) * tanhf(pg);
    float hn = sigmoid_xla(po) * tanhf(cn);
    float eps = normal_from_idx(k1a, k1b, (uint32_t)(R * 256 + h));
    hn = hn + eps * std_g[bb * 256 + h];
    ccur[(size_t)R * 256 + h] = cn;
    hcur[(size_t)R * 256 + h] = hn;
    hnv[r] = hn;
  }

  const float dw = decW[h], pw = pdfW[h];
#pragma unroll
  for (int r = 0; r < 8; ++r) {
    int rr = kg * 8 + r;
    float v = hnv[r] * dw;
    for (int off = 32; off; off >>= 1) v += __shfl_down(v, off);
    if (lane == 0) s_sredP[rr * 4 + (h >> 6)] = v;
    float v2 = hnv[r] * pw;
    for (int off = 32; off; off >>= 1) v2 += __shfl_down(v2, off);
    if (lane == 0) s_sredQ[rr * 4 + (h >> 6)] = v2;
  }
  __syncthreads();
  if (tid < 16) {
    int rr = tid;
    proj_g[R0 + rr] = ((s_sredP[rr * 4 + 0] + s_sredP[rr * 4 + 1]) +
                       (s_sredP[rr * 4 + 2] + s_sredP[rr * 4 + 3])) + decbp[0];
  } else if (tid < 32) {
    int rr = tid - 16;
    pdot_g[R0 + rr] = (s_sredQ[rr * 4 + 0] + s_sredQ[rr * 4 + 1]) +
                      (s_sredQ[rr * 4 + 2] + s_sredQ[rr * 4 + 3]);
  }
}

// ---------------- epilogue: final resample + means + output head ----------------

__launch_bounds__(256)
__global__ void darnn_kout(const float* __restrict__ proj_g, const float* __restrict__ pdot_g,
                           const float* __restrict__ ytl_prev, const float* __restrict__ hprev,
                           const float* __restrict__ ctx_g, const float* __restrict__ decW,
                           const float* __restrict__ decbp, const float* __restrict__ encWo,
                           const float* __restrict__ encbo, const float* __restrict__ pdfW,
                           const float* __restrict__ pdfbp,
                           uint32_t k2a, uint32_t k2b, float* __restrict__ out) {
  const int b = blockIdx.x, tid = threadIdx.x, bg = b >> 5, bloc = b & 31;
  const int lane = tid & 63;
  __shared__ float s_gp[1024], s_w[1024];
  __shared__ int s_srck[1024];
  __shared__ float s_ytlp[32], s_den[32], s_logit[32];
  __shared__ int s_row[32];
  __shared__ float s_hm[256], s_sred[8];

  if (tid < 32) s_ytlp[tid] = ytl_prev[bg * 32 + tid];
  for (int i = tid; i < 1024; i += 256) {
    int bl = i >> 5, k = i & 31;
    s_gp[i] = proj_g[k * 128 + bg * 32 + bl];
  }
  __syncthreads();
  for (int i = tid; i < 1024; i += 256) {
    int bl = i >> 5, k = i & 31;
    float p = s_gp[i];
    const float* gp = s_gp + bl * 32;
    int rank = 0;
    for (int kk = 0; kk < 32; ++kk) {
      float q = gp[kk];
      rank += (q < p) || (q == p && kk < k);
    }
    s_srck[bl * 32 + rank] = k;
    float wv = expf((pdot_g[k * 128 + bg * 32 + bl] + s_ytlp[bl] * pdfW[256]) + pdfbp[0]);
    s_w[bl * 32 + rank] = wv;
  }
  __syncthreads();
  if (tid < 32) {
    float s = 0.f;
    for (int bl = 0; bl < 32; ++bl) s += s_w[bl * 32 + tid];
    s_den[tid] = s;
  }
  __syncthreads();
  if (tid < 32) s_logit[tid] = logf(s_w[bloc * 32 + tid] / s_den[tid]);
  __syncthreads();
  if (tid < 32) {
    int ko = tid, r2 = ko * 128 + b;
    float best = gumbel_from_idx(k2a, k2b, (uint32_t)(r2 * 32)) + s_logit[0];
    int sv = 0;
    for (int k = 1; k < 32; ++k) {
      float v = gumbel_from_idx(k2a, k2b, (uint32_t)(r2 * 32 + k)) + s_logit[k];
      if (v > best) { best = v; sv = k; }
    }
    s_row[ko] = s_srck[bloc * 32 + sv] * 128 + b;
  }
  __syncthreads();
  {
    float s1 = 0.f;
    for (int k = 0; k < 32; ++k) s1 += hprev[(size_t)s_row[k] * 256 + tid];
    s_hm[tid] = s1 * 0.03125f;
  }
  __syncthreads();
  {
    int wvi = tid >> 6;
    float v1 = s_hm[tid] * decW[tid];
    float v2 = ctx_g[b * 256 + tid] * encWo[tid];
    for (int off = 32; off; off >>= 1) { v1 += __shfl_down(v1, off); v2 += __shfl_down(v2, off); }
    if (lane == 0) { s_sred[wvi] = v1; s_sred[4 + wvi] = v2; }
  }
  __syncthreads();
  if (tid == 0) {
    float d1 = (s_sred[0] + s_sred[1]) + (s_sred[2] + s_sred[3]);
    float d2 = (s_sred[4] + s_sred[5]) + (s_sred[6] + s_sred[7]);
    out[b] = ((d1 + decbp[0]) + d2) + encbo[0];
  }
}

extern "C" void kernel_launch(void* const* d_in, const int* in_sizes, int n_in,
                              void* d_out, int out_size, void* d_ws, size_t ws_size,
                              hipStream_t stream) {
  const float* enc   = (const float*)d_in[0];
  const float* yprev = (const float*)d_in[1];
  const float* W1    = (const float*)d_in[2];
  const float* b1    = (const float*)d_in[3];
  const float* W2    = (const float*)d_in[4];
  const float* b2    = (const float*)d_in[5];
  const float* fcW   = (const float*)d_in[6];
  const float* fcb   = (const float*)d_in[7];
  const float* varW  = (const float*)d_in[8];
  const float* varb  = (const float*)d_in[9];
  const float* Wih   = (const float*)d_in[10];
  const float* Whh   = (const float*)d_in[11];
  const float* bih   = (const float*)d_in[12];
  const float* bhh   = (const float*)d_in[13];
  const float* decW  = (const float*)d_in[14];
  const float* decb  = (const float*)d_in[15];
  const float* pdfW  = (const float*)d_in[16];
  const float* pdfb  = (const float*)d_in[17];
  const float* encWo = (const float*)d_in[18];
  const float* encbo = (const float*)d_in[19];

  float* ws = (float*)d_ws;
  size_t o = 0;
  float* encW1 = ws + o; o += (size_t)Bn * Tn * Hn;    // 1,048,576
  float* W1hT  = ws + o; o += (size_t)Hn * Hn;
  float* W1cT  = ws + o; o += (size_t)Hn * Hn;
  float* W1eT  = ws + o; o += (size_t)Hn * Hn;
  float* WhhT  = ws + o; o += (size_t)Hn * 4 * Hn;     // 262,144
  float* varWT = ws + o; o += (size_t)257 * Hn;        // 65,792
  float* hbuf0 = ws + o; o += (size_t)Kn * Bn * Hn;    // ping-pong h
  float* hbuf1 = ws + o; o += (size_t)Kn * Bn * Hn;
  float* cbuf0 = ws + o; o += (size_t)Kn * Bn * Hn;    // ping-pong c
  float* cbuf1 = ws + o; o += (size_t)Kn * Bn * Hn;
  float* ytl0  = ws + o; o += 128;                     // ping-pong ytl
  float* ytl1  = ws + o; o += 128;
  float* std_g = ws + o; o += (size_t)Bn * Hn;
  float* ctx_g = ws + o; o += (size_t)Bn * Hn;
  float* proj_g = ws + o; o += 4096;
  float* pdot_g = ws + o; o += 4096;
  int*   idxH  = (int*)(ws + o); o += 4096;
  int*   idxC  = (int*)(ws + o); o += 4096;
  if (ws_size < o * sizeof(float)) return;

  float* hb[2] = { hbuf0, hbuf1 };
  float* cb[2] = { cbuf0, cbuf1 };
  float* yb[2] = { ytl0, ytl1 };

  // zero the t=0 "previous" state (parity (0+1)&1 = 1)
  hipMemsetAsync(hbuf1, 0, (size_t)Kn * Bn * Hn * sizeof(float), stream);
  hipMemsetAsync(cbuf1, 0, (size_t)Kn * Bn * Hn * sizeof(float), stream);

  darnn_p0<<<1281, 256, 0, stream>>>(W1, Whh, varW, W1hT, W1cT, W1eT, WhhT, varWT);
  darnn_p1<<<Bn * Tn, 256, 0, stream>>>(enc, W1eT, b1, encW1);

  uint32_t k2pa = 0, k2pb = 0;
  for (int t = 0; t < Tn; ++t) {
    uint32_t f0, f1, k1a, k1b, k2a, k2b;
    tf2x32(0u, 42u, 0u, (uint32_t)t, f0, f1);
    tf2x32(f0, f1, 0u, 0u, k1a, k1b);
    tf2x32(f0, f1, 0u, 1u, k2a, k2b);
    int cur = t & 1, prv = (t + 1) & 1;

    darnn_ka<<<Bn, 256, 0, stream>>>(enc, yprev, W1hT, W1cT, encW1, W2, b2, fcW, fcb,
                                     varWT, varb, pdfW, pdfb,
                                     proj_g, pdot_g, yb[prv], hb[prv], cb[prv],
                                     idxH, idxC, yb[cur], std_g, ctx_g,
                                     t, k2pa, k2pb);
    darnn_k5<<<Kn * Bn / 16, 512, 0, stream>>>(hb[prv], cb[prv], idxH, idxC, WhhT,
                                               Wih, bih, bhh, yb[cur], std_g,
                                               decW, decb, pdfW, k1a, k1b,
                                               hb[cur], cb[cur], proj_g, pdot_g);
    k2pa = k2a; k2pb = k2b;
  }

  darnn_kout<<<Bn, 256, 0, stream>>>(proj_g, pdot_g, yb[1], hb[1], ctx_g,
                                     decW, decb, encWo, encbo, pdfW, pdfb,
                                     k2pa, k2pb, (float*)d_out);
}

// Round 4
// 3009.654 us; speedup vs baseline: 3.4823x; 1.2133x over previous
//
#include <hip/hip_runtime.h>
#include <cstdint>

// DA_RNN particle filter, B=128 T=32 H=256 K=32.
// Round 4: same 2-dispatch/step structure as round 3 (bit-exact, absmax 0.0),
// occupancy fixes only:
//   ka: 128 blk x 1024 thr (was 256 thr) — 4x waves for latency phases.
//   k5: 256 blk x 1024 thr, 16 rows/block, 4 rows/thread (was 512 thr, 8 rows/thread)
//       -> 4 waves/SIMD, half the per-thread LDS reads, 16 accumulators.
// ALL fp chains operand-for-operand identical to the verified bit-exact order.

#define Bn 128
#define Tn 32
#define Hn 256
#define Kn 32

__host__ __device__ inline void tf2x32(uint32_t k0, uint32_t k1, uint32_t x0, uint32_t x1,
                                       uint32_t &o0, uint32_t &o1) {
  uint32_t ks2 = k0 ^ k1 ^ 0x1BD11BDAu;
  x0 += k0; x1 += k1;
#define TFR(r) { x0 += x1; x1 = (x1 << r) | (x1 >> (32 - r)); x1 ^= x0; }
  TFR(13) TFR(15) TFR(26) TFR(6)
  x0 += k1;  x1 += ks2 + 1u;
  TFR(17) TFR(29) TFR(16) TFR(24)
  x0 += ks2; x1 += k0 + 2u;
  TFR(13) TFR(15) TFR(26) TFR(6)
  x0 += k0;  x1 += k1 + 3u;
  TFR(17) TFR(29) TFR(16) TFR(24)
  x0 += k1;  x1 += ks2 + 4u;
  TFR(13) TFR(15) TFR(26) TFR(6)
  x0 += ks2; x1 += k0 + 5u;
#undef TFR
  o0 = x0; o1 = x1;
}

__device__ __forceinline__ float erfinv_xla(float x) {
  float w = -log1pf(-x * x);
  float p;
  if (w < 5.0f) {
    w = w - 2.5f;
    p = 2.81022636e-08f;
    p = fmaf(p, w, 3.43273939e-07f);
    p = fmaf(p, w, -3.5233877e-06f);
    p = fmaf(p, w, -4.39150654e-06f);
    p = fmaf(p, w, 0.00021858087f);
    p = fmaf(p, w, -0.00125372503f);
    p = fmaf(p, w, -0.00417768164f);
    p = fmaf(p, w, 0.246640727f);
    p = fmaf(p, w, 1.50140941f);
  } else {
    w = sqrtf(w) - 3.0f;
    p = -0.000200214257f;
    p = fmaf(p, w, 0.000100950558f);
    p = fmaf(p, w, 0.00134934322f);
    p = fmaf(p, w, -0.00367342844f);
    p = fmaf(p, w, 0.00573950773f);
    p = fmaf(p, w, -0.0076224613f);
    p = fmaf(p, w, 0.00943887047f);
    p = fmaf(p, w, 1.00167406f);
    p = fmaf(p, w, 2.83297682f);
  }
  return p * x;
}

__device__ __forceinline__ float sigmoid_xla(float x) {
  return 0.5f + 0.5f * tanhf(0.5f * x);
}

__device__ __forceinline__ float u01_from_bits(uint32_t bits) {
  return __uint_as_float((bits >> 9) | 0x3F800000u) - 1.0f;
}

__device__ __forceinline__ float normal_from_idx(uint32_t ka, uint32_t kb, uint32_t idx) {
  uint32_t o0, o1; tf2x32(ka, kb, 0u, idx, o0, o1);
  float f = u01_from_bits(o0 ^ o1);
  const float LO = __uint_as_float(0xBF7FFFFFu);
  float u = fmaxf(LO, f * 2.0f + LO);
  return __uint_as_float(0x3FB504F3u) * erfinv_xla(u);
}

__device__ __forceinline__ float gumbel_from_idx(uint32_t ka, uint32_t kb, uint32_t idx) {
  uint32_t o0, o1; tf2x32(ka, kb, 0u, idx, o0, o1);
  float f = u01_from_bits(o0 ^ o1);
  const float TINY = __uint_as_float(0x00800000u);
  float u = fmaxf(TINY, f + TINY);
  return -logf(-logf(u));
}

// ---------------- precompute ----------------

__global__ void darnn_p0(const float* __restrict__ W1, const float* __restrict__ Whh,
                         const float* __restrict__ varW,
                         float* __restrict__ W1hT, float* __restrict__ W1cT,
                         float* __restrict__ W1eT, float* __restrict__ WhhT,
                         float* __restrict__ varWT) {
  int bid = blockIdx.x, tid = threadIdx.x;
  if (bid < 768) {
    int part = bid >> 8, j = bid & 255;
    float v = W1[tid * 768 + part * 256 + j];
    float* dst = (part == 0) ? W1hT : (part == 1) ? W1cT : W1eT;
    dst[j * 256 + tid] = v;
  } else if (bid < 1024) {
    int j = bid - 768;
    for (int idx = tid; idx < 1024; idx += 256) {
      int h = idx >> 2, q = idx & 3;
      WhhT[j * 1024 + idx] = Whh[(q * 256 + h) * 256 + j];
    }
  } else {
    int j2 = bid - 1024;  // 0..256
    varWT[j2 * 256 + tid] = varW[tid * 257 + j2];
  }
}

__global__ void darnn_p1(const float* __restrict__ enc, const float* __restrict__ W1eT,
                         const float* __restrict__ b1, float* __restrict__ encW1) {
  int bt = blockIdx.x, tid = threadIdx.x;
  __shared__ float se[256];
  se[tid] = enc[bt * 256 + tid];
  __syncthreads();
  float acc = 0.f;
  for (int j = 0; j < 256; ++j) acc = fmaf(se[j], W1eT[j * 256 + tid], acc);
  encW1[bt * 256 + tid] = acc + b1[tid];
}

// ---------------- per-step head kernel: sample(t-1) + means + attention + var ----

__launch_bounds__(1024)
__global__ void darnn_ka(const float* __restrict__ enc, const float* __restrict__ yprev,
                         const float* __restrict__ W1hT, const float* __restrict__ W1cT,
                         const float* __restrict__ encW1, const float* __restrict__ W2,
                         const float* __restrict__ b2p, const float* __restrict__ fcW,
                         const float* __restrict__ fcbp, const float* __restrict__ varWT,
                         const float* __restrict__ varb, const float* __restrict__ pdfW,
                         const float* __restrict__ pdfbp,
                         const float* __restrict__ proj_g, const float* __restrict__ pdot_g,
                         const float* __restrict__ ytl_prev,
                         const float* __restrict__ hprev, const float* __restrict__ cprev,
                         int* __restrict__ idxH_g, int* __restrict__ idxC_g,
                         float* __restrict__ ytl_cur, float* __restrict__ std_g,
                         float* __restrict__ ctx_g,
                         int t, uint32_t k2a, uint32_t k2b) {
  const int b = blockIdx.x, tid = threadIdx.x, bg = b >> 5, bloc = b & 31;
  __shared__ float s_gp[1024], s_w[1024];
  __shared__ int s_srck[1024];
  __shared__ float s_ytlp[32], s_den[32], s_logit[32];
  __shared__ int s_row[32], s_rowc[32];
  __shared__ float s_hm[256], s_cm[256], s_hmc[256], s_red[256];
  __shared__ float s_sc[32], s_beta[32];
  __shared__ float s_ytl;

  if (t > 0) {
    if (tid < 32) s_ytlp[tid] = ytl_prev[bg * 32 + tid];
    {
      int bl = tid >> 5, k = tid & 31;
      s_gp[tid] = proj_g[k * 128 + bg * 32 + bl];
    }
    __syncthreads();
    {
      int bl = tid >> 5, k = tid & 31;
      float p = s_gp[tid];
      const float* gp = s_gp + bl * 32;
      int rank = 0;
      for (int kk = 0; kk < 32; ++kk) {
        float q = gp[kk];
        rank += (q < p) || (q == p && kk < k);
      }
      s_srck[bl * 32 + rank] = k;
      // round-1 f1 order: exp((pdot + ytl*pdfW[256]) + pdfb)
      float wv = expf((pdot_g[k * 128 + bg * 32 + bl] + s_ytlp[bl] * pdfW[256]) + pdfbp[0]);
      s_w[bl * 32 + rank] = wv;
    }
    __syncthreads();
    if (tid < 32) {
      // denom: sum over group batches ASCENDING at fixed rank (round-1 f2 order)
      float s = 0.f;
      for (int bl = 0; bl < 32; ++bl) s += s_w[bl * 32 + tid];
      s_den[tid] = s;
    }
    __syncthreads();
    if (tid < 32) s_logit[tid] = logf(s_w[bloc * 32 + tid] / s_den[tid]);
    __syncthreads();
    if (tid < 32) {
      int ko = tid, r2 = ko * 128 + b;
      float best = gumbel_from_idx(k2a, k2b, (uint32_t)(r2 * 32)) + s_logit[0];
      int sv = 0;
      for (int k = 1; k < 32; ++k) {
        float v = gumbel_from_idx(k2a, k2b, (uint32_t)(r2 * 32 + k)) + s_logit[k];
        if (v > best) { best = v; sv = k; }
      }
      int sH = s_srck[bloc * 32 + sv];
      s_row[ko] = sH * 128 + b;     // h source row (sorted gather)
      s_rowc[ko] = sv * 128 + b;    // c source row (unsorted gather)
      idxH_g[ko * 128 + b] = sH * 128 + b;
      idxC_g[ko * 128 + b] = sv * 128 + b;
    }
  } else {
    if (tid < 32) {
      s_row[tid] = tid * 128 + b;
      s_rowc[tid] = tid * 128 + b;
      idxH_g[tid * 128 + b] = tid * 128 + b;
      idxC_g[tid * 128 + b] = tid * 128 + b;
    }
  }
  __syncthreads();

  // particle means, k ascending (round-1 k12 order), via indirection.
  // split h-mean / c-mean across two thread groups (independent chains).
  if (tid < 256) {
    float s1 = 0.f;
    for (int k = 0; k < 32; ++k) s1 += hprev[(size_t)s_row[k] * 256 + tid];
    s_hm[tid] = s1 * 0.03125f;
  } else if (tid < 512) {
    int j = tid & 255;
    float s2 = 0.f;
    for (int k = 0; k < 32; ++k) s2 += cprev[(size_t)s_rowc[k] * 256 + j];
    s_cm[j] = s2 * 0.03125f;
  }
  __syncthreads();
  // hmc GEMV: serial interleaved h/c chain (round-1 order)
  if (tid < 256) {
    float acc = 0.f;
    for (int j = 0; j < 256; ++j) {
      acc = fmaf(s_hm[j], W1hT[j * 256 + tid], acc);
      acc = fmaf(s_cm[j], W1cT[j * 256 + tid], acc);
    }
    s_hmc[tid] = acc;
  }
  __syncthreads();
  // attention scores (round-1 k3 tree): 16 waves, 2 tt each
  {
    int lane = tid & 63, wv = tid >> 6;
    for (int tt = wv * 2; tt < wv * 2 + 2; ++tt) {
      float p = 0.f;
      for (int hh = lane; hh < 256; hh += 64)
        p += tanhf(encW1[(b * 32 + tt) * 256 + hh] + s_hmc[hh]) * W2[hh];
      for (int off = 32; off; off >>= 1) p += __shfl_down(p, off);
      if (lane == 0) s_sc[tt] = p + b2p[0];
    }
  }
  __syncthreads();
  if (tid == 0) {
    float m = s_sc[0];
    for (int k = 1; k < 32; ++k) m = fmaxf(m, s_sc[k]);
    float s = 0.f;
    for (int k = 0; k < 32; ++k) { float e = expf(s_sc[k] - m); s_beta[k] = e; s += e; }
    for (int k = 0; k < 32; ++k) s_beta[k] /= s;
  }
  __syncthreads();
  // context + y_tilde (round-1 k3)
  if (tid < 256) {
    float cx = 0.f;
    for (int tt = 0; tt < 32; ++tt) cx = fmaf(s_beta[tt], enc[(b * 32 + tt) * 256 + tid], cx);
    ctx_g[b * 256 + tid] = cx;
    s_red[tid] = cx * fcW[tid];
  }
  __syncthreads();
  if (tid == 0) {
    float s = 0.f;
    for (int j = 0; j < 256; ++j) s += s_red[j];
    s += yprev[b * 32 + t] * fcW[256];
    s_ytl = s + fcbp[0];
    ytl_cur[b] = s_ytl;
  }
  __syncthreads();
  // var head -> std (round-1 k4 order, transposed weights)
  if (tid < 256) {
    float v = s_ytl * varWT[tid];
    for (int j = 0; j < 256; ++j) v = fmaf(s_hm[j], varWT[(1 + j) * 256 + tid], v);
    v += varb[tid];
    std_g[b * 256 + tid] = fmaxf(v, 0.f) + log1pf(expf(-fabsf(v)));
  }
}

// ---------------- per-step LSTM kernel: 16 rows/block, 4 rows/thread ----------------

__launch_bounds__(1024)
__global__ void darnn_k5(const float* __restrict__ hprev, const float* __restrict__ cprev,
                         const int* __restrict__ idxH_g, const int* __restrict__ idxC_g,
                         const float* __restrict__ WhhT, const float* __restrict__ Wih,
                         const float* __restrict__ bih, const float* __restrict__ bhh,
                         const float* __restrict__ ytl_cur, const float* __restrict__ std_g,
                         const float* __restrict__ decW, const float* __restrict__ decbp,
                         const float* __restrict__ pdfW,
                         uint32_t k1a, uint32_t k1b,
                         float* __restrict__ hcur, float* __restrict__ ccur,
                         float* __restrict__ proj_g, float* __restrict__ pdot_g) {
  const int R0 = blockIdx.x * 16, tid = threadIdx.x;
  const int h = tid & 255, kg = tid >> 8, lane = tid & 63;  // kg in [0,4): 4 rows each
  __shared__ __align__(16) float s_h[16 * 256];
  __shared__ int s_src[16], s_srcC[16];
  __shared__ float s_sredP[16 * 4], s_sredQ[16 * 4];

  if (tid < 16) { s_src[tid] = idxH_g[R0 + tid]; s_srcC[tid] = idxC_g[R0 + tid]; }
  __syncthreads();
  {
    const float4* hp = (const float4*)hprev;
    float4* sh4 = (float4*)s_h;
    int rr = tid >> 6, c4 = tid & 63;
    sh4[tid] = hp[(size_t)s_src[rr] * 64 + c4];
  }
  __syncthreads();

  float ai[4], af[4], ag[4], ao[4];
#pragma unroll
  for (int r = 0; r < 4; ++r) { ai[r] = af[r] = ag[r] = ao[r] = 0.f; }
  {
    const float4* wp = (const float4*)WhhT + h;
    const float* shr = s_h + kg * 4 * 256;
    for (int j = 0; j < 256; j += 4) {
      float4 w0 = wp[(j + 0) * 256];
      float4 w1 = wp[(j + 1) * 256];
      float4 w2 = wp[(j + 2) * 256];
      float4 w3 = wp[(j + 3) * 256];
#pragma unroll
      for (int r = 0; r < 4; ++r) {
        float4 h4 = *(const float4*)(shr + r * 256 + j);
        ai[r] = fmaf(h4.x, w0.x, ai[r]); ai[r] = fmaf(h4.y, w1.x, ai[r]);
        ai[r] = fmaf(h4.z, w2.x, ai[r]); ai[r] = fmaf(h4.w, w3.x, ai[r]);
        af[r] = fmaf(h4.x, w0.y, af[r]); af[r] = fmaf(h4.y, w1.y, af[r]);
        af[r] = fmaf(h4.z, w2.y, af[r]); af[r] = fmaf(h4.w, w3.y, af[r]);
        ag[r] = fmaf(h4.x, w0.z, ag[r]); ag[r] = fmaf(h4.y, w1.z, ag[r]);
        ag[r] = fmaf(h4.z, w2.z, ag[r]); ag[r] = fmaf(h4.w, w3.z, ag[r]);
        ao[r] = fmaf(h4.x, w0.w, ao[r]); ao[r] = fmaf(h4.y, w1.w, ao[r]);
        ao[r] = fmaf(h4.z, w2.w, ao[r]); ao[r] = fmaf(h4.w, w3.w, ao[r]);
      }
    }
  }

  const float bI = bih[h], bF = bih[256 + h], bG = bih[512 + h], bO = bih[768 + h];
  const float dI = bhh[h], dF = bhh[256 + h], dG = bhh[512 + h], dO = bhh[768 + h];
  const float wI = Wih[h], wF = Wih[256 + h], wG = Wih[512 + h], wO = Wih[768 + h];
  float hnv[4];
#pragma unroll
  for (int r = 0; r < 4; ++r) {
    int rr = kg * 4 + r, R = R0 + rr, bb = R & 127;
    float xb = ytl_cur[bb];
    float pi = ((xb * wI + bI) + ai[r]) + dI;
    float pf = ((xb * wF + bF) + af[r]) + dF;
    float pg = ((xb * wG + bG) + ag[r]) + dG;
    float po = ((xb * wO + bO) + ao[r]) + dO;
    float c_old = cprev[(size_t)s_srcC[rr] * 256 + h];
    float cn = sigmoid_xla(pf) * c_old + sigmoid_xla(pi) * tanhf(pg);
    float hn = sigmoid_xla(po) * tanhf(cn);
    float eps = normal_from_idx(k1a, k1b, (uint32_t)(R * 256 + h));
    hn = hn + eps * std_g[bb * 256 + h];
    ccur[(size_t)R * 256 + h] = cn;
    hcur[(size_t)R * 256 + h] = hn;
    hnv[r] = hn;
  }

  const float dw = decW[h], pw = pdfW[h];
#pragma unroll
  for (int r = 0; r < 4; ++r) {
    int rr = kg * 4 + r;
    float v = hnv[r] * dw;
    for (int off = 32; off; off >>= 1) v += __shfl_down(v, off);
    if (lane == 0) s_sredP[rr * 4 + (h >> 6)] = v;
    float v2 = hnv[r] * pw;
    for (int off = 32; off; off >>= 1) v2 += __shfl_down(v2, off);
    if (lane == 0) s_sredQ[rr * 4 + (h >> 6)] = v2;
  }
  __syncthreads();
  if (tid < 16) {
    int rr = tid;
    proj_g[R0 + rr] = ((s_sredP[rr * 4 + 0] + s_sredP[rr * 4 + 1]) +
                       (s_sredP[rr * 4 + 2] + s_sredP[rr * 4 + 3])) + decbp[0];
  } else if (tid < 32) {
    int rr = tid - 16;
    pdot_g[R0 + rr] = (s_sredQ[rr * 4 + 0] + s_sredQ[rr * 4 + 1]) +
                      (s_sredQ[rr * 4 + 2] + s_sredQ[rr * 4 + 3]);
  }
}

// ---------------- epilogue: final resample + means + output head ----------------

__launch_bounds__(256)
__global__ void darnn_kout(const float* __restrict__ proj_g, const float* __restrict__ pdot_g,
                           const float* __restrict__ ytl_prev, const float* __restrict__ hprev,
                           const float* __restrict__ ctx_g, const float* __restrict__ decW,
                           const float* __restrict__ decbp, const float* __restrict__ encWo,
                           const float* __restrict__ encbo, const float* __restrict__ pdfW,
                           const float* __restrict__ pdfbp,
                           uint32_t k2a, uint32_t k2b, float* __restrict__ out) {
  const int b = blockIdx.x, tid = threadIdx.x, bg = b >> 5, bloc = b & 31;
  const int lane = tid & 63;
  __shared__ float s_gp[1024], s_w[1024];
  __shared__ int s_srck[1024];
  __shared__ float s_ytlp[32], s_den[32], s_logit[32];
  __shared__ int s_row[32];
  __shared__ float s_hm[256], s_sred[8];

  if (tid < 32) s_ytlp[tid] = ytl_prev[bg * 32 + tid];
  for (int i = tid; i < 1024; i += 256) {
    int bl = i >> 5, k = i & 31;
    s_gp[i] = proj_g[k * 128 + bg * 32 + bl];
  }
  __syncthreads();
  for (int i = tid; i < 1024; i += 256) {
    int bl = i >> 5, k = i & 31;
    float p = s_gp[i];
    const float* gp = s_gp + bl * 32;
    int rank = 0;
    for (int kk = 0; kk < 32; ++kk) {
      float q = gp[kk];
      rank += (q < p) || (q == p && kk < k);
    }
    s_srck[bl * 32 + rank] = k;
    float wv = expf((pdot_g[k * 128 + bg * 32 + bl] + s_ytlp[bl] * pdfW[256]) + pdfbp[0]);
    s_w[bl * 32 + rank] = wv;
  }
  __syncthreads();
  if (tid < 32) {
    float s = 0.f;
    for (int bl = 0; bl < 32; ++bl) s += s_w[bl * 32 + tid];
    s_den[tid] = s;
  }
  __syncthreads();
  if (tid < 32) s_logit[tid] = logf(s_w[bloc * 32 + tid] / s_den[tid]);
  __syncthreads();
  if (tid < 32) {
    int ko = tid, r2 = ko * 128 + b;
    float best = gumbel_from_idx(k2a, k2b, (uint32_t)(r2 * 32)) + s_logit[0];
    int sv = 0;
    for (int k = 1; k < 32; ++k) {
      float v = gumbel_from_idx(k2a, k2b, (uint32_t)(r2 * 32 + k)) + s_logit[k];
      if (v > best) { best = v; sv = k; }
    }
    s_row[ko] = s_srck[bloc * 32 + sv] * 128 + b;
  }
  __syncthreads();
  {
    float s1 = 0.f;
    for (int k = 0; k < 32; ++k) s1 += hprev[(size_t)s_row[k] * 256 + tid];
    s_hm[tid] = s1 * 0.03125f;
  }
  __syncthreads();
  {
    int wvi = tid >> 6;
    float v1 = s_hm[tid] * decW[tid];
    float v2 = ctx_g[b * 256 + tid] * encWo[tid];
    for (int off = 32; off; off >>= 1) { v1 += __shfl_down(v1, off); v2 += __shfl_down(v2, off); }
    if (lane == 0) { s_sred[wvi] = v1; s_sred[4 + wvi] = v2; }
  }
  __syncthreads();
  if (tid == 0) {
    float d1 = (s_sred[0] + s_sred[1]) + (s_sred[2] + s_sred[3]);
    float d2 = (s_sred[4] + s_sred[5]) + (s_sred[6] + s_sred[7]);
    out[b] = ((d1 + decbp[0]) + d2) + encbo[0];
  }
}

extern "C" void kernel_launch(void* const* d_in, const int* in_sizes, int n_in,
                              void* d_out, int out_size, void* d_ws, size_t ws_size,
                              hipStream_t stream) {
  const float* enc   = (const float*)d_in[0];
  const float* yprev = (const float*)d_in[1];
  const float* W1    = (const float*)d_in[2];
  const float* b1    = (const float*)d_in[3];
  const float* W2    = (const float*)d_in[4];
  const float* b2    = (const float*)d_in[5];
  const float* fcW   = (const float*)d_in[6];
  const float* fcb   = (const float*)d_in[7];
  const float* varW  = (const float*)d_in[8];
  const float* varb  = (const float*)d_in[9];
  const float* Wih   = (const float*)d_in[10];
  const float* Whh   = (const float*)d_in[11];
  const float* bih   = (const float*)d_in[12];
  const float* bhh   = (const float*)d_in[13];
  const float* decW  = (const float*)d_in[14];
  const float* decb  = (const float*)d_in[15];
  const float* pdfW  = (const float*)d_in[16];
  const float* pdfb  = (const float*)d_in[17];
  const float* encWo = (const float*)d_in[18];
  const float* encbo = (const float*)d_in[19];

  float* ws = (float*)d_ws;
  size_t o = 0;
  float* encW1 = ws + o; o += (size_t)Bn * Tn * Hn;    // 1,048,576
  float* W1hT  = ws + o; o += (size_t)Hn * Hn;
  float* W1cT  = ws + o; o += (size_t)Hn * Hn;
  float* W1eT  = ws + o; o += (size_t)Hn * Hn;
  float* WhhT  = ws + o; o += (size_t)Hn * 4 * Hn;     // 262,144
  float* varWT = ws + o; o += (size_t)257 * Hn;        // 65,792
  float* hbuf0 = ws + o; o += (size_t)Kn * Bn * Hn;    // ping-pong h
  float* hbuf1 = ws + o; o += (size_t)Kn * Bn * Hn;
  float* cbuf0 = ws + o; o += (size_t)Kn * Bn * Hn;    // ping-pong c
  float* cbuf1 = ws + o; o += (size_t)Kn * Bn * Hn;
  float* ytl0  = ws + o; o += 128;                     // ping-pong ytl
  float* ytl1  = ws + o; o += 128;
  float* std_g = ws + o; o += (size_t)Bn * Hn;
  float* ctx_g = ws + o; o += (size_t)Bn * Hn;
  float* proj_g = ws + o; o += 4096;
  float* pdot_g = ws + o; o += 4096;
  int*   idxH  = (int*)(ws + o); o += 4096;
  int*   idxC  = (int*)(ws + o); o += 4096;
  if (ws_size < o * sizeof(float)) return;

  float* hb[2] = { hbuf0, hbuf1 };
  float* cb[2] = { cbuf0, cbuf1 };
  float* yb[2] = { ytl0, ytl1 };

  // zero the t=0 "previous" state (parity (0+1)&1 = 1)
  hipMemsetAsync(hbuf1, 0, (size_t)Kn * Bn * Hn * sizeof(float), stream);
  hipMemsetAsync(cbuf1, 0, (size_t)Kn * Bn * Hn * sizeof(float), stream);

  darnn_p0<<<1281, 256, 0, stream>>>(W1, Whh, varW, W1hT, W1cT, W1eT, WhhT, varWT);
  darnn_p1<<<Bn * Tn, 256, 0, stream>>>(enc, W1eT, b1, encW1);

  uint32_t k2pa = 0, k2pb = 0;
  for (int t = 0; t < Tn; ++t) {
    uint32_t f0, f1, k1a, k1b, k2a, k2b;
    tf2x32(0u, 42u, 0u, (uint32_t)t, f0, f1);
    tf2x32(f0, f1, 0u, 0u, k1a, k1b);
    tf2x32(f0, f1, 0u, 1u, k2a, k2b);
    int cur = t & 1, prv = (t + 1) & 1;

    darnn_ka<<<Bn, 1024, 0, stream>>>(enc, yprev, W1hT, W1cT, encW1, W2, b2, fcW, fcb,
                                      varWT, varb, pdfW, pdfb,
                                      proj_g, pdot_g, yb[prv], hb[prv], cb[prv],
                                      idxH, idxC, yb[cur], std_g, ctx_g,
                                      t, k2pa, k2pb);
    darnn_k5<<<Kn * Bn / 16, 1024, 0, stream>>>(hb[prv], cb[prv], idxH, idxC, WhhT,
                                                Wih, bih, bhh, yb[cur], std_g,
                                                decW, decb, pdfW, k1a, k1b,
                                                hb[cur], cb[cur], proj_g, pdot_g);
    k2pa = k2a; k2pb = k2b;
  }

  darnn_kout<<<Bn, 256, 0, stream>>>(proj_g, pdot_g, yb[1], hb[1], ctx_g,
                                     decW, decb, encWo, encbo, pdfW, pdfb,
                                     k2pa, k2pb, (float*)d_out);
}

// Round 5
// 2865.991 us; speedup vs baseline: 3.6569x; 1.0501x over previous
//
#include <hip/hip_runtime.h>
#include <cstdint>

// DA_RNN particle filter, B=128 T=32 H=256 K=32.
// Round 5: ONE dispatch per step. Block = (khalf, b): 256 blocks x 1024 thr.
// Each block redundantly computes the per-b head (resample idx, means, hmc GEMV,
// attention, ytl, var->std) into LDS, then its 16-row LSTM GEMM with
// software-prefetched weight stream (__launch_bounds__(1024,4) -> 128 VGPR cap).
// proj/pdot/ytl/h/c all ping-pong across dispatches (kernel boundary = sync).
// ALL fp chains operand-for-operand identical to the verified bit-exact order.

#define Bn 128
#define Tn 32
#define Hn 256
#define Kn 32

__host__ __device__ inline void tf2x32(uint32_t k0, uint32_t k1, uint32_t x0, uint32_t x1,
                                       uint32_t &o0, uint32_t &o1) {
  uint32_t ks2 = k0 ^ k1 ^ 0x1BD11BDAu;
  x0 += k0; x1 += k1;
#define TFR(r) { x0 += x1; x1 = (x1 << r) | (x1 >> (32 - r)); x1 ^= x0; }
  TFR(13) TFR(15) TFR(26) TFR(6)
  x0 += k1;  x1 += ks2 + 1u;
  TFR(17) TFR(29) TFR(16) TFR(24)
  x0 += ks2; x1 += k0 + 2u;
  TFR(13) TFR(15) TFR(26) TFR(6)
  x0 += k0;  x1 += k1 + 3u;
  TFR(17) TFR(29) TFR(16) TFR(24)
  x0 += k1;  x1 += ks2 + 4u;
  TFR(13) TFR(15) TFR(26) TFR(6)
  x0 += ks2; x1 += k0 + 5u;
#undef TFR
  o0 = x0; o1 = x1;
}

__device__ __forceinline__ float erfinv_xla(float x) {
  float w = -log1pf(-x * x);
  float p;
  if (w < 5.0f) {
    w = w - 2.5f;
    p = 2.81022636e-08f;
    p = fmaf(p, w, 3.43273939e-07f);
    p = fmaf(p, w, -3.5233877e-06f);
    p = fmaf(p, w, -4.39150654e-06f);
    p = fmaf(p, w, 0.00021858087f);
    p = fmaf(p, w, -0.00125372503f);
    p = fmaf(p, w, -0.00417768164f);
    p = fmaf(p, w, 0.246640727f);
    p = fmaf(p, w, 1.50140941f);
  } else {
    w = sqrtf(w) - 3.0f;
    p = -0.000200214257f;
    p = fmaf(p, w, 0.000100950558f);
    p = fmaf(p, w, 0.00134934322f);
    p = fmaf(p, w, -0.00367342844f);
    p = fmaf(p, w, 0.00573950773f);
    p = fmaf(p, w, -0.0076224613f);
    p = fmaf(p, w, 0.00943887047f);
    p = fmaf(p, w, 1.00167406f);
    p = fmaf(p, w, 2.83297682f);
  }
  return p * x;
}

__device__ __forceinline__ float sigmoid_xla(float x) {
  return 0.5f + 0.5f * tanhf(0.5f * x);
}

__device__ __forceinline__ float u01_from_bits(uint32_t bits) {
  return __uint_as_float((bits >> 9) | 0x3F800000u) - 1.0f;
}

__device__ __forceinline__ float normal_from_idx(uint32_t ka, uint32_t kb, uint32_t idx) {
  uint32_t o0, o1; tf2x32(ka, kb, 0u, idx, o0, o1);
  float f = u01_from_bits(o0 ^ o1);
  const float LO = __uint_as_float(0xBF7FFFFFu);
  float u = fmaxf(LO, f * 2.0f + LO);
  return __uint_as_float(0x3FB504F3u) * erfinv_xla(u);
}

__device__ __forceinline__ float gumbel_from_idx(uint32_t ka, uint32_t kb, uint32_t idx) {
  uint32_t o0, o1; tf2x32(ka, kb, 0u, idx, o0, o1);
  float f = u01_from_bits(o0 ^ o1);
  const float TINY = __uint_as_float(0x00800000u);
  float u = fmaxf(TINY, f + TINY);
  return -logf(-logf(u));
}

// ---------------- precompute ----------------

__global__ void darnn_p0(const float* __restrict__ W1, const float* __restrict__ Whh,
                         const float* __restrict__ varW,
                         float* __restrict__ W1hT, float* __restrict__ W1cT,
                         float* __restrict__ W1eT, float* __restrict__ WhhT,
                         float* __restrict__ varWT) {
  int bid = blockIdx.x, tid = threadIdx.x;
  if (bid < 768) {
    int part = bid >> 8, j = bid & 255;
    float v = W1[tid * 768 + part * 256 + j];
    float* dst = (part == 0) ? W1hT : (part == 1) ? W1cT : W1eT;
    dst[j * 256 + tid] = v;
  } else if (bid < 1024) {
    int j = bid - 768;
    for (int idx = tid; idx < 1024; idx += 256) {
      int h = idx >> 2, q = idx & 3;
      WhhT[j * 1024 + idx] = Whh[(q * 256 + h) * 256 + j];
    }
  } else {
    int j2 = bid - 1024;  // 0..256
    varWT[j2 * 256 + tid] = varW[tid * 257 + j2];
  }
}

__global__ void darnn_p1(const float* __restrict__ enc, const float* __restrict__ W1eT,
                         const float* __restrict__ b1, float* __restrict__ encW1) {
  int bt = blockIdx.x, tid = threadIdx.x;
  __shared__ float se[256];
  se[tid] = enc[bt * 256 + tid];
  __syncthreads();
  float acc = 0.f;
  for (int j = 0; j < 256; ++j) acc = fmaf(se[j], W1eT[j * 256 + tid], acc);
  encW1[bt * 256 + tid] = acc + b1[tid];
}

// ---------------- fused per-step kernel ----------------
// block bid: b = bid & 127, khalf = bid >> 7. Rows k = khalf*16 + [0,16).

__launch_bounds__(1024, 4)
__global__ void darnn_step(const float* __restrict__ enc, const float* __restrict__ yprev,
                           const float* __restrict__ W1hT, const float* __restrict__ W1cT,
                           const float* __restrict__ encW1, const float* __restrict__ W2,
                           const float* __restrict__ b2p, const float* __restrict__ fcW,
                           const float* __restrict__ fcbp, const float* __restrict__ varWT,
                           const float* __restrict__ varb, const float* __restrict__ WhhT,
                           const float* __restrict__ Wih, const float* __restrict__ bih,
                           const float* __restrict__ bhh, const float* __restrict__ decW,
                           const float* __restrict__ decbp, const float* __restrict__ pdfW,
                           const float* __restrict__ pdfbp,
                           const float* __restrict__ proj_p, const float* __restrict__ pdot_p,
                           const float* __restrict__ ytl_p,
                           const float* __restrict__ hprev, const float* __restrict__ cprev,
                           float* __restrict__ hcur, float* __restrict__ ccur,
                           float* __restrict__ proj_c, float* __restrict__ pdot_c,
                           float* __restrict__ ytl_c, float* __restrict__ ctx_g,
                           int t, uint32_t k1a, uint32_t k1b, uint32_t k2a, uint32_t k2b) {
  const int bid = blockIdx.x, tid = threadIdx.x;
  const int b = bid & 127, khalf = bid >> 7;
  const int bg = b >> 5, bloc = b & 31;
  const int h = tid & 255, kg = tid >> 8, lane = tid & 63;

  __shared__ __align__(16) float s_h[32 * 256];   // all 32 resampled h rows for b
  __shared__ float s_gp[1024], s_w[1024];
  __shared__ int s_srck[1024];
  __shared__ float s_ytlp[32], s_den[32], s_logit[32];
  __shared__ int s_rowH[32], s_rowC[32];
  __shared__ float s_hm[256], s_cm[256], s_hmc[256], s_red[256], s_std[256];
  __shared__ float s_sc[32], s_beta[32];
  __shared__ float s_ytl;
  __shared__ float s_sredP[16 * 4], s_sredQ[16 * 4];

  // ---- phase 0: resample indices for step t-1 (redundant per (khalf,b)) ----
  if (t > 0) {
    if (tid < 32) s_ytlp[tid] = ytl_p[bg * 32 + tid];
    {
      int bl = tid >> 5, k = tid & 31;
      s_gp[tid] = proj_p[k * 128 + bg * 32 + bl];
    }
    __syncthreads();
    {
      int bl = tid >> 5, k = tid & 31;
      float p = s_gp[tid];
      const float* gp = s_gp + bl * 32;
      int rank = 0;
      for (int kk = 0; kk < 32; ++kk) {
        float q = gp[kk];
        rank += (q < p) || (q == p && kk < k);
      }
      s_srck[bl * 32 + rank] = k;
      float wv = expf((pdot_p[k * 128 + bg * 32 + bl] + s_ytlp[bl] * pdfW[256]) + pdfbp[0]);
      s_w[bl * 32 + rank] = wv;
    }
    __syncthreads();
    if (tid < 32) {
      float s = 0.f;
      for (int bl = 0; bl < 32; ++bl) s += s_w[bl * 32 + tid];
      s_den[tid] = s;
    }
    __syncthreads();
    if (tid < 32) s_logit[tid] = logf(s_w[bloc * 32 + tid] / s_den[tid]);
    __syncthreads();
    if (tid < 32) {
      int ko = tid, r2 = ko * 128 + b;
      float best = gumbel_from_idx(k2a, k2b, (uint32_t)(r2 * 32)) + s_logit[0];
      int sv = 0;
      for (int k = 1; k < 32; ++k) {
        float v = gumbel_from_idx(k2a, k2b, (uint32_t)(r2 * 32 + k)) + s_logit[k];
        if (v > best) { best = v; sv = k; }
      }
      s_rowH[ko] = s_srck[bloc * 32 + sv] * 128 + b;  // sorted gather for h
      s_rowC[ko] = sv * 128 + b;                      // unsorted gather for c
    }
  } else {
    if (tid < 32) {
      s_rowH[tid] = tid * 128 + b;
      s_rowC[tid] = tid * 128 + b;
    }
  }
  __syncthreads();

  // ---- stage all 32 resampled h rows into LDS ----
  {
    const float4* hp = (const float4*)hprev;
    float4* sh4 = (float4*)s_h;
#pragma unroll
    for (int ii = 0; ii < 2; ++ii) {
      int i = tid + ii * 1024;
      int rr = i >> 6, c4 = i & 63;
      sh4[i] = hp[(size_t)s_rowH[rr] * 64 + c4];
    }
  }
  __syncthreads();

  // ---- head: means (k ascending, round-1 order) ----
  if (tid < 256) {
    float s1 = 0.f;
    for (int k = 0; k < 32; ++k) s1 += s_h[k * 256 + tid];
    s_hm[tid] = s1 * 0.03125f;
  } else if (tid < 512) {
    int j = tid & 255;
    float s2 = 0.f;
    for (int k = 0; k < 32; ++k) s2 += cprev[(size_t)s_rowC[k] * 256 + j];
    s_cm[j] = s2 * 0.03125f;
  }
  __syncthreads();
  // hmc GEMV: serial interleaved h/c chain (round-1 order)
  if (tid < 256) {
    float acc = 0.f;
    for (int j = 0; j < 256; ++j) {
      acc = fmaf(s_hm[j], W1hT[j * 256 + tid], acc);
      acc = fmaf(s_cm[j], W1cT[j * 256 + tid], acc);
    }
    s_hmc[tid] = acc;
  }
  __syncthreads();
  // attention scores (round-1 k3 tree): 16 waves, 2 tt each
  {
    int wv = tid >> 6;
    for (int tt = wv * 2; tt < wv * 2 + 2; ++tt) {
      float p = 0.f;
      for (int hh = lane; hh < 256; hh += 64)
        p += tanhf(encW1[(b * 32 + tt) * 256 + hh] + s_hmc[hh]) * W2[hh];
      for (int off = 32; off; off >>= 1) p += __shfl_down(p, off);
      if (lane == 0) s_sc[tt] = p + b2p[0];
    }
  }
  __syncthreads();
  if (tid == 0) {
    float m = s_sc[0];
    for (int k = 1; k < 32; ++k) m = fmaxf(m, s_sc[k]);
    float s = 0.f;
    for (int k = 0; k < 32; ++k) { float e = expf(s_sc[k] - m); s_beta[k] = e; s += e; }
    for (int k = 0; k < 32; ++k) s_beta[k] /= s;
  }
  __syncthreads();
  // context + y_tilde (round-1 k3)
  if (tid < 256) {
    float cx = 0.f;
    for (int tt = 0; tt < 32; ++tt) cx = fmaf(s_beta[tt], enc[(b * 32 + tt) * 256 + tid], cx);
    if (khalf == 0) ctx_g[b * 256 + tid] = cx;
    s_red[tid] = cx * fcW[tid];
  }
  __syncthreads();
  if (tid == 0) {
    float s = 0.f;
    for (int j = 0; j < 256; ++j) s += s_red[j];
    s += yprev[b * 32 + t] * fcW[256];
    s_ytl = s + fcbp[0];
    if (khalf == 0) ytl_c[b] = s_ytl;
  }
  __syncthreads();
  // var head -> std (round-1 k4 order), kept in LDS
  if (tid < 256) {
    float v = s_ytl * varWT[tid];
    for (int j = 0; j < 256; ++j) v = fmaf(s_hm[j], varWT[(1 + j) * 256 + tid], v);
    v += varb[tid];
    s_std[tid] = fmaxf(v, 0.f) + log1pf(expf(-fabsf(v)));
  }
  __syncthreads();

  // ---- LSTM GEMM: 16 rows (k = khalf*16 + [0,16)), 4 rows/thread ----
  float ai[4], af[4], ag[4], ao[4];
#pragma unroll
  for (int r = 0; r < 4; ++r) { ai[r] = af[r] = ag[r] = ao[r] = 0.f; }
  {
    const float4* wp = (const float4*)WhhT + h;
    const float* shr = s_h + (khalf * 16 + kg * 4) * 256;
    // software prefetch: keep next j-chunk's 4 weight float4s in flight
    float4 wa0 = wp[0 * 256], wa1 = wp[1 * 256], wa2 = wp[2 * 256], wa3 = wp[3 * 256];
    for (int j = 0; j < 256; j += 4) {
      int jn = (j + 4) & 255;  // final iter wraps to 0 (dummy, in-bounds)
      float4 wb0 = wp[(jn + 0) * 256];
      float4 wb1 = wp[(jn + 1) * 256];
      float4 wb2 = wp[(jn + 2) * 256];
      float4 wb3 = wp[(jn + 3) * 256];
#pragma unroll
      for (int r = 0; r < 4; ++r) {
        float4 h4 = *(const float4*)(shr + r * 256 + j);
        ai[r] = fmaf(h4.x, wa0.x, ai[r]); ai[r] = fmaf(h4.y, wa1.x, ai[r]);
        ai[r] = fmaf(h4.z, wa2.x, ai[r]); ai[r] = fmaf(h4.w, wa3.x, ai[r]);
        af[r] = fmaf(h4.x, wa0.y, af[r]); af[r] = fmaf(h4.y, wa1.y, af[r]);
        af[r] = fmaf(h4.z, wa2.y, af[r]); af[r] = fmaf(h4.w, wa3.y, af[r]);
        ag[r] = fmaf(h4.x, wa0.z, ag[r]); ag[r] = fmaf(h4.y, wa1.z, ag[r]);
        ag[r] = fmaf(h4.z, wa2.z, ag[r]); ag[r] = fmaf(h4.w, wa3.z, ag[r]);
        ao[r] = fmaf(h4.x, wa0.w, ao[r]); ao[r] = fmaf(h4.y, wa1.w, ao[r]);
        ao[r] = fmaf(h4.z, wa2.w, ao[r]); ao[r] = fmaf(h4.w, wa3.w, ao[r]);
      }
      wa0 = wb0; wa1 = wb1; wa2 = wb2; wa3 = wb3;
    }
  }

  const float bI = bih[h], bF = bih[256 + h], bG = bih[512 + h], bO = bih[768 + h];
  const float dI = bhh[h], dF = bhh[256 + h], dG = bhh[512 + h], dO = bhh[768 + h];
  const float wI = Wih[h], wF = Wih[256 + h], wG = Wih[512 + h], wO = Wih[768 + h];
  float hnv[4];
#pragma unroll
  for (int r = 0; r < 4; ++r) {
    int rl = kg * 4 + r;               // local row 0..15
    int k = khalf * 16 + rl, R = k * 128 + b;
    float xb = s_ytl;
    float pi = ((xb * wI + bI) + ai[r]) + dI;
    float pf = ((xb * wF + bF) + af[r]) + dF;
    float pg = ((xb * wG + bG) + ag[r]) + dG;
    float po = ((xb * wO + bO) + ao[r]) + dO;
    float c_old = cprev[(size_t)s_rowC[k] * 256 + h];
    float cn = sigmoid_xla(pf) * c_old + sigmoid_xla(pi) * tanhf(pg);
    float hn = sigmoid_xla(po) * tanhf(cn);
    float eps = normal_from_idx(k1a, k1b, (uint32_t)(R * 256 + h));
    hn = hn + eps * s_std[h];
    ccur[(size_t)R * 256 + h] = cn;
    hcur[(size_t)R * 256 + h] = hn;
    hnv[r] = hn;
  }

  const float dw = decW[h], pw = pdfW[h];
#pragma unroll
  for (int r = 0; r < 4; ++r) {
    int rl = kg * 4 + r;
    float v = hnv[r] * dw;
    for (int off = 32; off; off >>= 1) v += __shfl_down(v, off);
    if (lane == 0) s_sredP[rl * 4 + (h >> 6)] = v;
    float v2 = hnv[r] * pw;
    for (int off = 32; off; off >>= 1) v2 += __shfl_down(v2, off);
    if (lane == 0) s_sredQ[rl * 4 + (h >> 6)] = v2;
  }
  __syncthreads();
  if (tid < 16) {
    int rl = tid, k = khalf * 16 + rl;
    proj_c[k * 128 + b] = ((s_sredP[rl * 4 + 0] + s_sredP[rl * 4 + 1]) +
                           (s_sredP[rl * 4 + 2] + s_sredP[rl * 4 + 3])) + decbp[0];
  } else if (tid < 32) {
    int rl = tid - 16, k = khalf * 16 + rl;
    pdot_c[k * 128 + b] = (s_sredQ[rl * 4 + 0] + s_sredQ[rl * 4 + 1]) +
                          (s_sredQ[rl * 4 + 2] + s_sredQ[rl * 4 + 3]);
  }
}

// ---------------- epilogue: final resample + means + output head ----------------

__launch_bounds__(256)
__global__ void darnn_kout(const float* __restrict__ proj_g, const float* __restrict__ pdot_g,
                           const float* __restrict__ ytl_prev, const float* __restrict__ hprev,
                           const float* __restrict__ ctx_g, const float* __restrict__ decW,
                           const float* __restrict__ decbp, const float* __restrict__ encWo,
                           const float* __restrict__ encbo, const float* __restrict__ pdfW,
                           const float* __restrict__ pdfbp,
                           uint32_t k2a, uint32_t k2b, float* __restrict__ out) {
  const int b = blockIdx.x, tid = threadIdx.x, bg = b >> 5, bloc = b & 31;
  const int lane = tid & 63;
  __shared__ float s_gp[1024], s_w[1024];
  __shared__ int s_srck[1024];
  __shared__ float s_ytlp[32], s_den[32], s_logit[32];
  __shared__ int s_row[32];
  __shared__ float s_hm[256], s_sred[8];

  if (tid < 32) s_ytlp[tid] = ytl_prev[bg * 32 + tid];
  for (int i = tid; i < 1024; i += 256) {
    int bl = i >> 5, k = i & 31;
    s_gp[i] = proj_g[k * 128 + bg * 32 + bl];
  }
  __syncthreads();
  for (int i = tid; i < 1024; i += 256) {
    int bl = i >> 5, k = i & 31;
    float p = s_gp[i];
    const float* gp = s_gp + bl * 32;
    int rank = 0;
    for (int kk = 0; kk < 32; ++kk) {
      float q = gp[kk];
      rank += (q < p) || (q == p && kk < k);
    }
    s_srck[bl * 32 + rank] = k;
    float wv = expf((pdot_g[k * 128 + bg * 32 + bl] + s_ytlp[bl] * pdfW[256]) + pdfbp[0]);
    s_w[bl * 32 + rank] = wv;
  }
  __syncthreads();
  if (tid < 32) {
    float s = 0.f;
    for (int bl = 0; bl < 32; ++bl) s += s_w[bl * 32 + tid];
    s_den[tid] = s;
  }
  __syncthreads();
  if (tid < 32) s_logit[tid] = logf(s_w[bloc * 32 + tid] / s_den[tid]);
  __syncthreads();
  if (tid < 32) {
    int ko = tid, r2 = ko * 128 + b;
    float best = gumbel_from_idx(k2a, k2b, (uint32_t)(r2 * 32)) + s_logit[0];
    int sv = 0;
    for (int k = 1; k < 32; ++k) {
      float v = gumbel_from_idx(k2a, k2b, (uint32_t)(r2 * 32 + k)) + s_logit[k];
      if (v > best) { best = v; sv = k; }
    }
    s_row[ko] = s_srck[bloc * 32 + sv] * 128 + b;
  }
  __syncthreads();
  {
    float s1 = 0.f;
    for (int k = 0; k < 32; ++k) s1 += hprev[(size_t)s_row[k] * 256 + tid];
    s_hm[tid] = s1 * 0.03125f;
  }
  __syncthreads();
  {
    int wvi = tid >> 6;
    float v1 = s_hm[tid] * decW[tid];
    float v2 = ctx_g[b * 256 + tid] * encWo[tid];
    for (int off = 32; off; off >>= 1) { v1 += __shfl_down(v1, off); v2 += __shfl_down(v2, off); }
    if (lane == 0) { s_sred[wvi] = v1; s_sred[4 + wvi] = v2; }
  }
  __syncthreads();
  if (tid == 0) {
    float d1 = (s_sred[0] + s_sred[1]) + (s_sred[2] + s_sred[3]);
    float d2 = (s_sred[4] + s_sred[5]) + (s_sred[6] + s_sred[7]);
    out[b] = ((d1 + decbp[0]) + d2) + encbo[0];
  }
}

extern "C" void kernel_launch(void* const* d_in, const int* in_sizes, int n_in,
                              void* d_out, int out_size, void* d_ws, size_t ws_size,
                              hipStream_t stream) {
  const float* enc   = (const float*)d_in[0];
  const float* yprev = (const float*)d_in[1];
  const float* W1    = (const float*)d_in[2];
  const float* b1    = (const float*)d_in[3];
  const float* W2    = (const float*)d_in[4];
  const float* b2    = (const float*)d_in[5];
  const float* fcW   = (const float*)d_in[6];
  const float* fcb   = (const float*)d_in[7];
  const float* varW  = (const float*)d_in[8];
  const float* varb  = (const float*)d_in[9];
  const float* Wih   = (const float*)d_in[10];
  const float* Whh   = (const float*)d_in[11];
  const float* bih   = (const float*)d_in[12];
  const float* bhh   = (const float*)d_in[13];
  const float* decW  = (const float*)d_in[14];
  const float* decb  = (const float*)d_in[15];
  const float* pdfW  = (const float*)d_in[16];
  const float* pdfb  = (const float*)d_in[17];
  const float* encWo = (const float*)d_in[18];
  const float* encbo = (const float*)d_in[19];

  float* ws = (float*)d_ws;
  size_t o = 0;
  float* encW1 = ws + o; o += (size_t)Bn * Tn * Hn;    // 1,048,576
  float* W1hT  = ws + o; o += (size_t)Hn * Hn;
  float* W1cT  = ws + o; o += (size_t)Hn * Hn;
  float* W1eT  = ws + o; o += (size_t)Hn * Hn;
  float* WhhT  = ws + o; o += (size_t)Hn * 4 * Hn;     // 262,144
  float* varWT = ws + o; o += (size_t)257 * Hn;        // 65,792
  float* hbuf0 = ws + o; o += (size_t)Kn * Bn * Hn;    // ping-pong h
  float* hbuf1 = ws + o; o += (size_t)Kn * Bn * Hn;
  float* cbuf0 = ws + o; o += (size_t)Kn * Bn * Hn;    // ping-pong c
  float* cbuf1 = ws + o; o += (size_t)Kn * Bn * Hn;
  float* ytl0  = ws + o; o += 128;                     // ping-pong ytl
  float* ytl1  = ws + o; o += 128;
  float* ctx_g = ws + o; o += (size_t)Bn * Hn;
  float* proj0 = ws + o; o += 4096;                    // ping-pong proj
  float* proj1 = ws + o; o += 4096;
  float* pdot0 = ws + o; o += 4096;                    // ping-pong pdot
  float* pdot1 = ws + o; o += 4096;
  if (ws_size < o * sizeof(float)) return;

  float* hb[2] = { hbuf0, hbuf1 };
  float* cb[2] = { cbuf0, cbuf1 };
  float* yb[2] = { ytl0, ytl1 };
  float* pp[2] = { proj0, proj1 };
  float* pq[2] = { pdot0, pdot1 };

  // zero the t=0 "previous" state (parity (0+1)&1 = 1)
  hipMemsetAsync(hbuf1, 0, (size_t)Kn * Bn * Hn * sizeof(float), stream);
  hipMemsetAsync(cbuf1, 0, (size_t)Kn * Bn * Hn * sizeof(float), stream);

  darnn_p0<<<1281, 256, 0, stream>>>(W1, Whh, varW, W1hT, W1cT, W1eT, WhhT, varWT);
  darnn_p1<<<Bn * Tn, 256, 0, stream>>>(enc, W1eT, b1, encW1);

  uint32_t k2pa = 0, k2pb = 0;
  for (int t = 0; t < Tn; ++t) {
    uint32_t f0, f1, k1a, k1b, k2a, k2b;
    tf2x32(0u, 42u, 0u, (uint32_t)t, f0, f1);
    tf2x32(f0, f1, 0u, 0u, k1a, k1b);
    tf2x32(f0, f1, 0u, 1u, k2a, k2b);
    int cur = t & 1, prv = (t + 1) & 1;

    darnn_step<<<2 * Bn, 1024, 0, stream>>>(enc, yprev, W1hT, W1cT, encW1, W2, b2,
                                            fcW, fcb, varWT, varb, WhhT, Wih, bih, bhh,
                                            decW, decb, pdfW, pdfb,
                                            pp[prv], pq[prv], yb[prv], hb[prv], cb[prv],
                                            hb[cur], cb[cur], pp[cur], pq[cur], yb[cur],
                                            ctx_g, t, k1a, k1b, k2pa, k2pb);
    k2pa = k2a; k2pb = k2b;
  }

  darnn_kout<<<Bn, 256, 0, stream>>>(pp[1], pq[1], yb[1], hb[1], ctx_g,
                                     decW, decb, encWo, encbo, pdfW, pdfb,
                                     k2pa, k2pb, (float*)d_out);
}